// Round 7
// baseline (212.648 us; speedup 1.0000x reference)
//
#include <hip/hip_runtime.h>
#include <math.h>

#define RES     32
#define GCELLS  (RES * RES * RES)       // 32768
#define NPTS    32768
#define BATCH   64
#define NPLANES 3
#define EPS_PD  1e-6f
#define WREG_F  25.0f

#define NB      256                     // 1 block per CU
#define NT      1024
#define NWAVES  (NT / 64)
#define QCELLS  (GCELLS / 4)            // 8192 cells per quarter

#define PACKED_BYTES ((size_t)BATCH * GCELLS * 4)          // 8 MiB u8x4 table
#define PART_OFF     PACKED_BYTES
#define CNT_OFF      (PACKED_BYTES + (size_t)NB * 4)
#define WS_NEED      (CNT_OFF + (size_t)(BATCH + 1) * 4)

typedef float        f4 __attribute__((ext_vector_type(4)));
typedef unsigned int u32;
typedef u32          u4 __attribute__((ext_vector_type(4)));

// ---------------------------------------------------------------------------
// helpers
// ---------------------------------------------------------------------------
__device__ __forceinline__ u32 quant_cell(float x, float y, float z, float v) {
    const u32 ux = (u32)fmaf(x, 255.0f, 128.0f);   // round_half_up((c+0.5)*255)
    const u32 uy = (u32)fmaf(y, 255.0f, 128.0f);
    const u32 uz = (u32)fmaf(z, 255.0f, 128.0f);
    const u32 uv = (u32)fmaf(v, 255.0f, 0.5f);     // round(v*255)
    return ux | (uy << 8) | (uz << 16) | (uv << 24);
}

__device__ __forceinline__ float gather_acc(
    const float* f, const u32* tab,
    const float* nx, const float* ny, const float* nz,
    const float* dd, const float* sc)
{
    const float SHIFT  = 0.5f + EPS_PD;
    const float IOFF   = -32.0f * EPS_PD;
    const float INV255 = 1.0f / 255.0f;

    float acc = 0.0f;
    #pragma unroll
    for (int p = 0; p < 8; ++p) {
        const float px = f[3*p], py = f[3*p+1], pz = f[3*p+2];
        const float pxs = px + SHIFT, pys = py + SHIFT, pzs = pz + SHIFT;
        #pragma unroll
        for (int pl = 0; pl < NPLANES; ++pl) {
            const float tt  = (px*nx[pl] + py*ny[pl] + pz*nz[pl] + dd[pl]) * sc[pl];
            const float qxs = fmaf(-tt, nx[pl], pxs);
            const float qys = fmaf(-tt, ny[pl], pys);
            const float qzs = fmaf(-tt, nz[pl], pzs);
            int ix = (int)fmaf(qxs, 32.0f, IOFF);
            int iy = (int)fmaf(qys, 32.0f, IOFF);
            int iz = (int)fmaf(qzs, 32.0f, IOFF);
            ix = min(max(ix, 0), RES - 1);
            iy = min(max(iy, 0), RES - 1);
            iz = min(max(iz, 0), RES - 1);
            const u32 gbyte = ((u32)ix << 12) + ((u32)iy << 7) + ((u32)iz << 2);
            const u32 cell  = *(const u32*)((const char*)tab + gbyte);
            const float dx = fmaf((float)(cell & 255u),         -INV255, qxs);
            const float dy = fmaf((float)((cell >> 8) & 255u),  -INV255, qys);
            const float dz = fmaf((float)((cell >> 16) & 255u), -INV255, qzs);
            const float w  = fmaf((float)(cell >> 24),          -INV255, 1.0f);
            acc = fmaf(__builtin_amdgcn_sqrtf(dx*dx + dy*dy + dz*dz), w, acc);
        }
    }
    return acc;
}

__device__ __forceinline__ float reg_term(const float* __restrict__ planes, int b) {
    float nv[3][3];
    #pragma unroll
    for (int p = 0; p < NPLANES; ++p) {
        const float nxv = planes[((p * BATCH + b) << 2) + 0];
        const float nyv = planes[((p * BATCH + b) << 2) + 1];
        const float nzv = planes[((p * BATCH + b) << 2) + 2];
        float nrm = fmaxf(sqrtf(nxv*nxv + nyv*nyv + nzv*nzv), 1e-12f);
        nv[p][0] = nxv / nrm; nv[p][1] = nyv / nrm; nv[p][2] = nzv / nrm;
    }
    float r = 0.0f;
    #pragma unroll
    for (int i = 0; i < 3; ++i)
        #pragma unroll
        for (int j = 0; j < 3; ++j) {
            const float m = nv[i][j] * nv[j][i] - (i == j ? 1.0f : 0.0f);
            r += m * m;
        }
    return r;
}

// ---------------------------------------------------------------------------
// Fused kernel: per-batch 4-block barrier instead of grid.sync.
//   phase 1: pack own quarter -> global + own LDS quarter (pc loads overlap)
//   batch barrier (device-scope counter, siblings are same-XCD -> L2-local)
//   phase 2: stage 3 sibling quarters from L2, gather, block-reduce
//   last-done block folds the final reduction + reg term.
// ---------------------------------------------------------------------------
__global__ __launch_bounds__(NT, 4) void fused_batch_kernel(
    const float* __restrict__ pc,      // (B, N, 3)
    const float* __restrict__ aux,     // (B*G, 3)
    const float* __restrict__ vox,     // (B*G)
    const float* __restrict__ planes,  // (3, B, 4)
    u32* __restrict__ packed,          // (B*G) u8x4
    float* __restrict__ part,          // (NB)
    u32* __restrict__ cnt,             // (BATCH+1), zeroed by memset node
    float* __restrict__ out)
{
    __shared__ u32   tab[GCELLS];      // 128 KiB
    __shared__ float wsum[NWAVES];
    __shared__ int   lastflag;

    const int t    = threadIdx.x;
    const int blk  = blockIdx.x;
    const int xcd  = blk & 7;
    const int slot = blk >> 3;
    const int b    = xcd * 8 + (slot >> 2);    // 4 sibling blocks per batch, same XCD
    const int c    = slot & 3;                 // quarter index

    // ---- pc loads first: HBM latency hides under the pack phase ----
    const f4* pc4 = (const f4*)pc
                  + (((size_t)(b * NPTS + c * 8192) * 3) >> 2)
                  + (size_t)t * 6;
    f4 A[6];
    #pragma unroll
    for (int i = 0; i < 6; ++i) A[i] = __builtin_nontemporal_load(pc4 + i);

    // ---- phase 1: pack own quarter (2 u4-groups/thread) ----
    const size_t g0 = ((size_t)b * GCELLS + (size_t)c * QCELLS) >> 2;  // u4 index
    #pragma unroll
    for (int i = 0; i < 2; ++i) {
        const size_t gk = g0 + (size_t)i * NT + t;
        const f4 a  = __builtin_nontemporal_load((const f4*)aux + 3 * gk + 0);
        const f4 bf = __builtin_nontemporal_load((const f4*)aux + 3 * gk + 1);
        const f4 cf = __builtin_nontemporal_load((const f4*)aux + 3 * gk + 2);
        const f4 v  = __builtin_nontemporal_load((const f4*)vox + gk);
        u4 o;
        o[0] = quant_cell(a.x, a.y, a.z, v.x);
        o[1] = quant_cell(a.w, bf.x, bf.y, v.y);
        o[2] = quant_cell(bf.z, bf.w, cf.x, v.z);
        o[3] = quant_cell(cf.y, cf.z, cf.w, v.w);
        *((u4*)packed + gk) = o;                       // for siblings (L2)
        const int lk = c * (QCELLS / 4) + i * NT + t;  // own LDS quarter
        *(u4*)&tab[lk * 4] = o;
    }

    // ---- batch barrier: wait for the 3 sibling quarters ----
    __threadfence();                                   // release packed stores
    __syncthreads();
    if (t == 0) {
        atomicAdd(&cnt[b], 1u);
        while (__hip_atomic_load(&cnt[b], __ATOMIC_ACQUIRE,
                                 __HIP_MEMORY_SCOPE_AGENT) < 4u)
            __builtin_amdgcn_s_sleep(8);
    }
    __syncthreads();

    // ---- phase 2: stage sibling quarters (6 u4/thread from L2) ----
    const u4* gt = (const u4*)packed + (size_t)b * (GCELLS / 4);
    #pragma unroll
    for (int q = 0; q < 4; ++q) {
        if (q == c) continue;
        #pragma unroll
        for (int i = 0; i < 2; ++i) {
            const int k = q * (QCELLS / 4) + i * NT + t;
            *(u4*)&tab[k * 4] = gt[k];
        }
    }

    float nx[3], ny[3], nz[3], dd[3], sc[3];
    #pragma unroll
    for (int pl = 0; pl < NPLANES; ++pl) {
        const float* P = planes + ((pl * BATCH + b) << 2);
        nx[pl] = P[0]; ny[pl] = P[1]; nz[pl] = P[2]; dd[pl] = P[3];
        sc[pl] = 2.0f / (nx[pl]*nx[pl] + ny[pl]*ny[pl] + nz[pl]*nz[pl]);
    }

    __syncthreads();

    float acc = gather_acc((const float*)A, tab, nx, ny, nz, dd, sc);

    #pragma unroll
    for (int off = 32; off > 0; off >>= 1)
        acc += __shfl_down(acc, off);
    if ((t & 63) == 0) wsum[t >> 6] = acc;
    __syncthreads();
    if (t == 0) {
        float s = 0.0f;
        #pragma unroll
        for (int w = 0; w < NWAVES; ++w) s += wsum[w];
        part[blk] = s;
        __threadfence();                               // release part[blk]
        const u32 old = atomicAdd(&cnt[BATCH], 1u);
        lastflag = (old == NB - 1) ? 1 : 0;
    }
    __syncthreads();

    // ---- last-done block: final reduction + reg term ----
    if (lastflag) {
        __threadfence();                               // acquire all part[]
        float val = (t < NB) ? part[t] * (1.0f / (float)BATCH) : 0.0f;
        if (t < BATCH) val += reg_term(planes, t) * (WREG_F / (float)BATCH);

        #pragma unroll
        for (int off = 32; off > 0; off >>= 1)
            val += __shfl_down(val, off);
        if ((t & 63) == 0) wsum[t >> 6] = val;
        __syncthreads();
        if (t == 0) {
            float s = 0.0f;
            #pragma unroll
            for (int w = 0; w < NWAVES; ++w) s += wsum[w];
            out[0] = s;
        }
    }
}

// ===========================================================================
// Fallback (ws too small): R4's proven 3-kernel pipeline.
// ===========================================================================
#define PACK_BLOCKS 2048

__device__ __forceinline__ int swizzle_chunk(int bid) {
    return (bid & 7) * (PACK_BLOCKS / 8) + (bid >> 3);
}

__global__ __launch_bounds__(256) void pack_u8_kernel(
    const float* __restrict__ aux,
    const float* __restrict__ vox,
    u32* __restrict__ packed)
{
    const int chunk = swizzle_chunk(blockIdx.x);
    const int i = chunk * 256 + threadIdx.x;

    const f4* a4 = (const f4*)aux + (size_t)i * 3;
    const f4 a = __builtin_nontemporal_load(a4 + 0);
    const f4 b = __builtin_nontemporal_load(a4 + 1);
    const f4 c = __builtin_nontemporal_load(a4 + 2);
    const f4 v = __builtin_nontemporal_load((const f4*)vox + i);

    u4 o;
    o[0] = quant_cell(a.x, a.y, a.z, v.x);
    o[1] = quant_cell(a.w, b.x, b.y, v.y);
    o[2] = quant_cell(b.z, b.w, c.x, v.z);
    o[3] = quant_cell(c.y, c.z, c.w, v.w);
    *((u4*)packed + i) = o;
}

__global__ __launch_bounds__(NT, 4) void sym_lds_kernel(
    const float* __restrict__ pc,
    const u32* __restrict__ packed,
    const float* __restrict__ planes,
    float* __restrict__ part)
{
    __shared__ u32   tab[GCELLS];
    __shared__ float wsum[NWAVES];

    const int t    = threadIdx.x;
    const int blk  = blockIdx.x;
    const int xcd  = blk & 7;
    const int slot = blk >> 3;
    const int b    = xcd * 8 + (slot >> 2);
    const int c    = slot & 3;

    const f4* pc4 = (const f4*)pc
                  + (((size_t)(b * NPTS + c * 8192) * 3) >> 2)
                  + (size_t)t * 6;
    f4 A[6];
    #pragma unroll
    for (int i = 0; i < 6; ++i) A[i] = __builtin_nontemporal_load(pc4 + i);

    const u4* gt = (const u4*)packed + (size_t)b * (GCELLS / 4);
    #pragma unroll
    for (int i = 0; i < 8; ++i) {
        const int k = i * NT + t;
        *(u4*)&tab[k * 4] = gt[k];
    }

    float nx[3], ny[3], nz[3], dd[3], sc[3];
    #pragma unroll
    for (int pl = 0; pl < NPLANES; ++pl) {
        const float* P = planes + ((pl * BATCH + b) << 2);
        nx[pl] = P[0]; ny[pl] = P[1]; nz[pl] = P[2]; dd[pl] = P[3];
        sc[pl] = 2.0f / (nx[pl]*nx[pl] + ny[pl]*ny[pl] + nz[pl]*nz[pl]);
    }

    __syncthreads();

    float acc = gather_acc((const float*)A, tab, nx, ny, nz, dd, sc);

    #pragma unroll
    for (int off = 32; off > 0; off >>= 1)
        acc += __shfl_down(acc, off);
    if ((t & 63) == 0) wsum[t >> 6] = acc;
    __syncthreads();
    if (t == 0) {
        float s = 0.0f;
        #pragma unroll
        for (int w = 0; w < NWAVES; ++w) s += wsum[w];
        part[blk] = s;
    }
}

__global__ __launch_bounds__(256) void finalize_kernel(
    const float* __restrict__ part, int n_part,
    const float* __restrict__ planes,
    float* __restrict__ out)
{
    __shared__ float sdata[256];

    float s = 0.0f;
    for (int i = threadIdx.x; i < n_part; i += 256)
        s += part[i];

    float r = 0.0f;
    if (threadIdx.x < BATCH)
        r = reg_term(planes, threadIdx.x);

    float val = s * (1.0f / (float)BATCH) + r * (WREG_F / (float)BATCH);

    sdata[threadIdx.x] = val;
    __syncthreads();
    #pragma unroll
    for (int off = 128; off > 0; off >>= 1) {
        if (threadIdx.x < off) sdata[threadIdx.x] += sdata[threadIdx.x + off];
        __syncthreads();
    }
    if (threadIdx.x == 0) out[0] = sdata[0];
}

// ---------------------------------------------------------------------------
extern "C" void kernel_launch(void* const* d_in, const int* in_sizes, int n_in,
                              void* d_out, int out_size, void* d_ws, size_t ws_size,
                              hipStream_t stream)
{
    const float* pc     = (const float*)d_in[0];
    const float* aux    = (const float*)d_in[1];
    const float* vox    = (const float*)d_in[2];
    const float* planes = (const float*)d_in[3];
    float* out = (float*)d_out;

    u32*   packed = (u32*)d_ws;
    float* part   = (float*)((char*)d_ws + PART_OFF);
    u32*   cnt    = (u32*)((char*)d_ws + CNT_OFF);

    if (ws_size >= WS_NEED) {
        hipMemsetAsync(cnt, 0, (BATCH + 1) * sizeof(u32), stream);
        fused_batch_kernel<<<NB, NT, 0, stream>>>(
            pc, aux, vox, planes, packed, part, cnt, out);
    } else if (ws_size >= PACKED_BYTES + NB * sizeof(float)) {
        pack_u8_kernel<<<PACK_BLOCKS, 256, 0, stream>>>(aux, vox, packed);
        sym_lds_kernel<<<NB, NT, 0, stream>>>(pc, packed, planes, part);
        finalize_kernel<<<1, 256, 0, stream>>>(part, NB, planes, out);
    }
}

// Round 8
// 39.736 us; speedup vs baseline: 5.3515x; 5.3515x over previous
//
#include <hip/hip_runtime.h>
#include <math.h>

#define RES     32
#define GCELLS  (RES * RES * RES)       // 32768
#define NPTS    32768
#define BATCH   64
#define NPLANES 3
#define EPS_PD  1e-6f
#define WREG_F  25.0f

#define NB      256                     // sym blocks: 1 per CU, 4 per batch
#define NT      1024
#define NWAVES  (NT / 64)

#define PACK_BLOCKS 2048

#define PACKED_BYTES ((size_t)BATCH * GCELLS * 4)          // 8 MiB u8x4 table
#define PART_OFF     PACKED_BYTES
#define CNT_OFF      (PACKED_BYTES + (size_t)NB * 4)
#define WS_NEED      (CNT_OFF + 4)

typedef float        f4 __attribute__((ext_vector_type(4)));
typedef unsigned int u32;
typedef u32          u4 __attribute__((ext_vector_type(4)));

// ---------------------------------------------------------------------------
// helpers
// ---------------------------------------------------------------------------
__device__ __forceinline__ u32 quant_cell(float x, float y, float z, float v) {
    const u32 ux = (u32)fmaf(x, 255.0f, 128.0f);   // round_half_up((c+0.5)*255)
    const u32 uy = (u32)fmaf(y, 255.0f, 128.0f);
    const u32 uz = (u32)fmaf(z, 255.0f, 128.0f);
    const u32 uv = (u32)fmaf(v, 255.0f, 0.5f);     // round(v*255)
    return ux | (uy << 8) | (uz << 16) | (uv << 24);
}

__device__ __forceinline__ float reg_term(const float* __restrict__ planes, int b) {
    float nv[3][3];
    #pragma unroll
    for (int p = 0; p < NPLANES; ++p) {
        const float nxv = planes[((p * BATCH + b) << 2) + 0];
        const float nyv = planes[((p * BATCH + b) << 2) + 1];
        const float nzv = planes[((p * BATCH + b) << 2) + 2];
        float nrm = fmaxf(sqrtf(nxv*nxv + nyv*nyv + nzv*nzv), 1e-12f);
        nv[p][0] = nxv / nrm; nv[p][1] = nyv / nrm; nv[p][2] = nzv / nrm;
    }
    float r = 0.0f;
    #pragma unroll
    for (int i = 0; i < 3; ++i)
        #pragma unroll
        for (int j = 0; j < 3; ++j) {
            const float m = nv[i][j] * nv[j][i] - (i == j ? 1.0f : 0.0f);
            r += m * m;
        }
    return r;
}

// ---------------------------------------------------------------------------
// Kernel 1: quantize (aux.xyz, vox) -> u8x4 table, XCD-swizzled so each
// XCD's L2 holds the 8 batch tables (1 MB) its sym blocks will stage.
// ---------------------------------------------------------------------------
__device__ __forceinline__ int swizzle_chunk(int bid) {
    return (bid & 7) * (PACK_BLOCKS / 8) + (bid >> 3);
}

__global__ __launch_bounds__(256) void pack_u8_kernel(
    const float* __restrict__ aux,
    const float* __restrict__ vox,
    u32* __restrict__ packed)
{
    const int chunk = swizzle_chunk(blockIdx.x);
    const int i = chunk * 256 + threadIdx.x;        // group of 4 cells

    const f4* a4 = (const f4*)aux + (size_t)i * 3;
    const f4 a = __builtin_nontemporal_load(a4 + 0);
    const f4 b = __builtin_nontemporal_load(a4 + 1);
    const f4 c = __builtin_nontemporal_load(a4 + 2);
    const f4 v = __builtin_nontemporal_load((const f4*)vox + i);

    u4 o;
    o[0] = quant_cell(a.x, a.y, a.z, v.x);
    o[1] = quant_cell(a.w, b.x, b.y, v.y);
    o[2] = quant_cell(b.z, b.w, c.x, v.z);
    o[3] = quant_cell(c.y, c.z, c.w, v.w);
    *((u4*)packed + i) = o;            // normal store: table stays in this L2
}

// ---------------------------------------------------------------------------
// Kernel 2: stage table to LDS, two-phase gather (all 24 LDS loads in
// flight before consumption), block reduce; LAST block folds the final
// reduction + reg term (one atomic per block, NO spinning).
// ---------------------------------------------------------------------------
__global__ __launch_bounds__(NT, 4) void sym_lds_kernel(
    const float* __restrict__ pc,      // (B, N, 3)
    const u32* __restrict__ packed,    // (B*G) u8x4
    const float* __restrict__ planes,  // (3, B, 4)
    float* __restrict__ part,          // (NB)
    u32* __restrict__ cnt,             // (1), zeroed by memset each replay
    float* __restrict__ out)
{
    __shared__ u32   tab[GCELLS];      // 128 KiB
    __shared__ float wsum[NWAVES];
    __shared__ int   lastflag;

    const int t    = threadIdx.x;
    const int blk  = blockIdx.x;
    const int xcd  = blk & 7;
    const int slot = blk >> 3;
    const int b    = xcd * 8 + (slot >> 2);    // batch (same XCD as its packer)
    const int c    = slot & 3;                 // quarter of the batch's points

    // ---- pc loads first: HBM latency hides under table staging ----
    const f4* pc4 = (const f4*)pc
                  + (((size_t)(b * NPTS + c * 8192) * 3) >> 2)
                  + (size_t)t * 6;
    f4 A[6];
    #pragma unroll
    for (int i = 0; i < 6; ++i) A[i] = __builtin_nontemporal_load(pc4 + i);

    // ---- stage the batch table from L2 (8 x 16 B per thread, linear) ----
    const u4* gt = (const u4*)packed + (size_t)b * (GCELLS / 4);
    #pragma unroll
    for (int i = 0; i < 8; ++i) {
        const int k = i * NT + t;
        *(u4*)&tab[k * 4] = gt[k];
    }

    // ---- block-uniform plane constants ----
    float nx[3], ny[3], nz[3], dd[3], sc[3];
    #pragma unroll
    for (int pl = 0; pl < NPLANES; ++pl) {
        const float* P = planes + ((pl * BATCH + b) << 2);
        nx[pl] = P[0]; ny[pl] = P[1]; nz[pl] = P[2]; dd[pl] = P[3];
        sc[pl] = 2.0f / (nx[pl]*nx[pl] + ny[pl]*ny[pl] + nz[pl]*nz[pl]);
    }

    __syncthreads();

    const float* f = (const float*)A;
    const float SHIFT  = 0.5f + EPS_PD;        // fold +0.5 and +eps into q
    const float IOFF   = -32.0f * EPS_PD;      // undo eps in the index path
    const float INV255 = 1.0f / 255.0f;

    // ---- phase A: compute all 24 reflections, issue all 24 LDS gathers ----
    float tt[24];
    u32   cell[24];
    #pragma unroll
    for (int p = 0; p < 8; ++p) {
        const float px = f[3*p], py = f[3*p+1], pz = f[3*p+2];
        const float pxs = px + SHIFT, pys = py + SHIFT, pzs = pz + SHIFT;
        #pragma unroll
        for (int pl = 0; pl < NPLANES; ++pl) {
            const int k = p * 3 + pl;
            const float tk = (px*nx[pl] + py*ny[pl] + pz*nz[pl] + dd[pl]) * sc[pl];
            tt[k] = tk;
            const float qxs = fmaf(-tk, nx[pl], pxs);
            const float qys = fmaf(-tk, ny[pl], pys);
            const float qzs = fmaf(-tk, nz[pl], pzs);
            int ix = (int)fmaf(qxs, 32.0f, IOFF);
            int iy = (int)fmaf(qys, 32.0f, IOFF);
            int iz = (int)fmaf(qzs, 32.0f, IOFF);
            ix = min(max(ix, 0), RES - 1);
            iy = min(max(iy, 0), RES - 1);
            iz = min(max(iz, 0), RES - 1);
            const u32 gbyte = ((u32)ix << 12) + ((u32)iy << 7) + ((u32)iz << 2);
            cell[k] = *(const u32*)((const char*)tab + gbyte);
        }
    }

    // ---- phase B: consume ----
    float acc = 0.0f;
    #pragma unroll
    for (int p = 0; p < 8; ++p) {
        const float pxs = f[3*p] + SHIFT, pys = f[3*p+1] + SHIFT, pzs = f[3*p+2] + SHIFT;
        #pragma unroll
        for (int pl = 0; pl < NPLANES; ++pl) {
            const int k = p * 3 + pl;
            const u32 cl = cell[k];
            const float qxs = fmaf(-tt[k], nx[pl], pxs);
            const float qys = fmaf(-tt[k], ny[pl], pys);
            const float qzs = fmaf(-tt[k], nz[pl], pzs);
            const float dx = fmaf((float)(cl & 255u),         -INV255, qxs);
            const float dy = fmaf((float)((cl >> 8) & 255u),  -INV255, qys);
            const float dz = fmaf((float)((cl >> 16) & 255u), -INV255, qzs);
            const float w  = fmaf((float)(cl >> 24),          -INV255, 1.0f);
            acc = fmaf(__builtin_amdgcn_sqrtf(dx*dx + dy*dy + dz*dz), w, acc);
        }
    }

    // ---- block reduce ----
    #pragma unroll
    for (int off = 32; off > 0; off >>= 1)
        acc += __shfl_down(acc, off);
    if ((t & 63) == 0) wsum[t >> 6] = acc;
    __syncthreads();
    if (t == 0) {
        float s = 0.0f;
        #pragma unroll
        for (int w = 0; w < NWAVES; ++w) s += wsum[w];
        // agent-scope release store: visible across XCDs to the last block
        __hip_atomic_store(&part[blk], s, __ATOMIC_RELEASE,
                           __HIP_MEMORY_SCOPE_AGENT);
        const u32 old = __hip_atomic_fetch_add(cnt, 1u, __ATOMIC_ACQ_REL,
                                               __HIP_MEMORY_SCOPE_AGENT);
        lastflag = (old == NB - 1) ? 1 : 0;
    }
    __syncthreads();

    // ---- last-arriving block: final reduction + reg term (no waiting) ----
    if (lastflag) {
        float val = 0.0f;
        if (t < NB)
            val = __hip_atomic_load(&part[t], __ATOMIC_ACQUIRE,
                                    __HIP_MEMORY_SCOPE_AGENT) * (1.0f / (float)BATCH);
        if (t < BATCH)
            val += reg_term(planes, t) * (WREG_F / (float)BATCH);

        #pragma unroll
        for (int off = 32; off > 0; off >>= 1)
            val += __shfl_down(val, off);
        if ((t & 63) == 0) wsum[t >> 6] = val;
        __syncthreads();
        if (t == 0) {
            float s = 0.0f;
            #pragma unroll
            for (int w = 0; w < NWAVES; ++w) s += wsum[w];
            out[0] = s;
        }
    }
}

// ---------------------------------------------------------------------------
// Fallback finalize (only used if ws too small for the packed path).
// ---------------------------------------------------------------------------
__global__ __launch_bounds__(256) void finalize_kernel(
    const float* __restrict__ part, int n_part,
    const float* __restrict__ planes,
    float* __restrict__ out)
{
    __shared__ float sdata[256];

    float s = 0.0f;
    for (int i = threadIdx.x; i < n_part; i += 256)
        s += part[i];

    float r = 0.0f;
    if (threadIdx.x < BATCH)
        r = reg_term(planes, threadIdx.x);

    float val = s * (1.0f / (float)BATCH) + r * (WREG_F / (float)BATCH);

    sdata[threadIdx.x] = val;
    __syncthreads();
    #pragma unroll
    for (int off = 128; off > 0; off >>= 1) {
        if (threadIdx.x < off) sdata[threadIdx.x] += sdata[threadIdx.x + off];
        __syncthreads();
    }
    if (threadIdx.x == 0) out[0] = sdata[0];
}

__global__ __launch_bounds__(256) void sym_fallback_kernel(
    const float* __restrict__ pc,
    const float* __restrict__ aux,
    const float* __restrict__ vox,
    const float* __restrict__ planes,
    float* __restrict__ part)
{
    const int chunk = swizzle_chunk(blockIdx.x);
    const int b  = chunk >> 5;
    const int cb = chunk & 31;

    float nx[3], ny[3], nz[3], dd[3], sc[3];
    #pragma unroll
    for (int pl = 0; pl < NPLANES; ++pl) {
        const float* P = planes + ((pl * BATCH + b) << 2);
        nx[pl] = P[0]; ny[pl] = P[1]; nz[pl] = P[2]; dd[pl] = P[3];
        sc[pl] = 2.0f / (nx[pl]*nx[pl] + ny[pl]*ny[pl] + nz[pl]*nz[pl]);
    }

    const int p0 = b * NPTS + cb * 1024 + threadIdx.x * 4;
    const f4* pc4 = (const f4*)pc + (size_t)(p0 >> 2) * 3;
    const f4 A  = __builtin_nontemporal_load(pc4 + 0);
    const f4 Bv = __builtin_nontemporal_load(pc4 + 1);
    const f4 C  = __builtin_nontemporal_load(pc4 + 2);

    const float px[4] = {A.x, A.w, Bv.z, C.y};
    const float py[4] = {A.y, Bv.x, Bv.w, C.z};
    const float pz[4] = {A.z, Bv.y, C.x, C.w};

    float acc = 0.0f;
    #pragma unroll
    for (int pt = 0; pt < 4; ++pt) {
        #pragma unroll
        for (int pl = 0; pl < NPLANES; ++pl) {
            const float tt = (px[pt]*nx[pl] + py[pt]*ny[pl] + pz[pt]*nz[pl]
                              + dd[pl]) * sc[pl];
            const float qx = px[pt] - tt * nx[pl];
            const float qy = py[pt] - tt * ny[pl];
            const float qz = pz[pt] - tt * nz[pl];
            int ix = (int)((qx + 0.5f) * (float)RES);
            int iy = (int)((qy + 0.5f) * (float)RES);
            int iz = (int)((qz + 0.5f) * (float)RES);
            ix = min(RES - 1, max(0, ix));
            iy = min(RES - 1, max(0, iy));
            iz = min(RES - 1, max(0, iz));
            const int gi = b * GCELLS + (ix << 10) + (iy << 5) + iz;
            const float v  = vox[gi];
            const float dx = qx - aux[gi*3+0] + EPS_PD;
            const float dy = qy - aux[gi*3+1] + EPS_PD;
            const float dz = qz - aux[gi*3+2] + EPS_PD;
            acc += sqrtf(dx*dx + dy*dy + dz*dz) * (1.0f - v);
        }
    }

    #pragma unroll
    for (int off = 32; off > 0; off >>= 1)
        acc += __shfl_down(acc, off);

    __shared__ float ws[4];
    if ((threadIdx.x & 63) == 0) ws[threadIdx.x >> 6] = acc;
    __syncthreads();
    if (threadIdx.x == 0)
        part[blockIdx.x] = ws[0] + ws[1] + ws[2] + ws[3];
}

// ---------------------------------------------------------------------------
extern "C" void kernel_launch(void* const* d_in, const int* in_sizes, int n_in,
                              void* d_out, int out_size, void* d_ws, size_t ws_size,
                              hipStream_t stream)
{
    const float* pc     = (const float*)d_in[0];
    const float* aux    = (const float*)d_in[1];
    const float* vox    = (const float*)d_in[2];
    const float* planes = (const float*)d_in[3];
    float* out = (float*)d_out;

    if (ws_size >= WS_NEED) {
        u32*   packed = (u32*)d_ws;
        float* part   = (float*)((char*)d_ws + PART_OFF);
        u32*   cnt    = (u32*)((char*)d_ws + CNT_OFF);
        hipMemsetAsync(cnt, 0, sizeof(u32), stream);
        pack_u8_kernel<<<PACK_BLOCKS, 256, 0, stream>>>(aux, vox, packed);
        sym_lds_kernel<<<NB, NT, 0, stream>>>(pc, packed, planes, part, cnt, out);
    } else {
        float* part = (float*)d_ws;
        sym_fallback_kernel<<<PACK_BLOCKS, 256, 0, stream>>>(pc, aux, vox, planes, part);
        finalize_kernel<<<1, 256, 0, stream>>>(part, PACK_BLOCKS, planes, out);
    }
}

// Round 9
// 36.022 us; speedup vs baseline: 5.9032x; 1.1031x over previous
//
#include <hip/hip_runtime.h>
#include <math.h>

#define RES     32
#define GCELLS  (RES * RES * RES)       // 32768
#define NPTS    32768
#define BATCH   64
#define NPLANES 3
#define EPS_PD  1e-6f
#define WREG_F  25.0f

#define NB      256                     // sym blocks: 1 per CU, 4 per batch
#define NT      1024
#define NWAVES  (NT / 64)

#define PACK_BLOCKS 2048
#define PACKED_BYTES ((size_t)BATCH * GCELLS * 4)    // 8 MiB u8x4 table

typedef float        f4 __attribute__((ext_vector_type(4)));
typedef unsigned int u32;
typedef u32          u4 __attribute__((ext_vector_type(4)));

// ---------------------------------------------------------------------------
// helpers
// ---------------------------------------------------------------------------
__device__ __forceinline__ u32 quant_cell(float x, float y, float z, float v) {
    const u32 ux = (u32)fmaf(x, 255.0f, 128.0f);   // round_half_up((c+0.5)*255)
    const u32 uy = (u32)fmaf(y, 255.0f, 128.0f);
    const u32 uz = (u32)fmaf(z, 255.0f, 128.0f);
    const u32 uv = (u32)fmaf(v, 255.0f, 0.5f);     // round(v*255)
    return ux | (uy << 8) | (uz << 16) | (uv << 24);
}

__device__ __forceinline__ float reg_term(const float* __restrict__ planes, int b) {
    float nv[3][3];
    #pragma unroll
    for (int p = 0; p < NPLANES; ++p) {
        const float nxv = planes[((p * BATCH + b) << 2) + 0];
        const float nyv = planes[((p * BATCH + b) << 2) + 1];
        const float nzv = planes[((p * BATCH + b) << 2) + 2];
        float nrm = fmaxf(sqrtf(nxv*nxv + nyv*nyv + nzv*nzv), 1e-12f);
        nv[p][0] = nxv / nrm; nv[p][1] = nyv / nrm; nv[p][2] = nzv / nrm;
    }
    float r = 0.0f;
    #pragma unroll
    for (int i = 0; i < 3; ++i)
        #pragma unroll
        for (int j = 0; j < 3; ++j) {
            const float m = nv[i][j] * nv[j][i] - (i == j ? 1.0f : 0.0f);
            r += m * m;
        }
    return r;
}

// ---------------------------------------------------------------------------
// Kernel 1: quantize (aux.xyz, vox) -> u8x4 table, XCD-swizzled so each
// XCD's L2 holds the 8 batch tables (1 MB) its sym blocks will stage.
// ---------------------------------------------------------------------------
__device__ __forceinline__ int swizzle_chunk(int bid) {
    return (bid & 7) * (PACK_BLOCKS / 8) + (bid >> 3);
}

__global__ __launch_bounds__(256) void pack_u8_kernel(
    const float* __restrict__ aux,
    const float* __restrict__ vox,
    u32* __restrict__ packed)
{
    const int chunk = swizzle_chunk(blockIdx.x);
    const int i = chunk * 256 + threadIdx.x;        // group of 4 cells

    const f4* a4 = (const f4*)aux + (size_t)i * 3;
    const f4 a = __builtin_nontemporal_load(a4 + 0);
    const f4 b = __builtin_nontemporal_load(a4 + 1);
    const f4 c = __builtin_nontemporal_load(a4 + 2);
    const f4 v = __builtin_nontemporal_load((const f4*)vox + i);

    u4 o;
    o[0] = quant_cell(a.x, a.y, a.z, v.x);
    o[1] = quant_cell(a.w, b.x, b.y, v.y);
    o[2] = quant_cell(b.z, b.w, c.x, v.z);
    o[3] = quant_cell(c.y, c.z, c.w, v.w);
    *((u4*)packed + i) = o;            // normal store: table stays in this L2
}

// ---------------------------------------------------------------------------
// Kernel 2: stage table to LDS; gather in two-phase CHUNKS OF 4 POINTS
// (12 LDS loads in flight, VGPR-safe); block reduce -> part[blk].
// ---------------------------------------------------------------------------
__global__ __launch_bounds__(NT, 4) void sym_lds_kernel(
    const float* __restrict__ pc,      // (B, N, 3)
    const u32* __restrict__ packed,    // (B*G) u8x4
    const float* __restrict__ planes,  // (3, B, 4)
    float* __restrict__ part)          // (NB)
{
    __shared__ u32   tab[GCELLS];      // 128 KiB
    __shared__ float wsum[NWAVES];

    const int t    = threadIdx.x;
    const int blk  = blockIdx.x;
    const int xcd  = blk & 7;
    const int slot = blk >> 3;
    const int b    = xcd * 8 + (slot >> 2);    // batch (same XCD as its packer)
    const int c    = slot & 3;                 // quarter of the batch's points

    // ---- pc loads first: HBM latency hides under table staging ----
    const f4* pc4 = (const f4*)pc
                  + (((size_t)(b * NPTS + c * 8192) * 3) >> 2)
                  + (size_t)t * 6;
    f4 A[6];
    #pragma unroll
    for (int i = 0; i < 6; ++i) A[i] = __builtin_nontemporal_load(pc4 + i);

    // ---- stage the batch table from L2 (8 x 16 B per thread, linear) ----
    const u4* gt = (const u4*)packed + (size_t)b * (GCELLS / 4);
    #pragma unroll
    for (int i = 0; i < 8; ++i) {
        const int k = i * NT + t;
        *(u4*)&tab[k * 4] = gt[k];
    }

    // ---- block-uniform plane constants ----
    float nx[3], ny[3], nz[3], dd[3], sc[3];
    #pragma unroll
    for (int pl = 0; pl < NPLANES; ++pl) {
        const float* P = planes + ((pl * BATCH + b) << 2);
        nx[pl] = P[0]; ny[pl] = P[1]; nz[pl] = P[2]; dd[pl] = P[3];
        sc[pl] = 2.0f / (nx[pl]*nx[pl] + ny[pl]*ny[pl] + nz[pl]*nz[pl]);
    }

    __syncthreads();

    const float* f = (const float*)A;
    const float SHIFT  = 0.5f + EPS_PD;        // fold +0.5 and +eps into q
    const float IOFF   = -32.0f * EPS_PD;      // undo eps in the index path
    const float INV255 = 1.0f / 255.0f;

    float acc = 0.0f;

    // ---- 2 chunks of 4 points: phase A computes 12 reflections and issues
    //      12 ds_read_b32; phase B consumes. ~85 VGPR, no spill. ----
    #pragma unroll
    for (int ch = 0; ch < 2; ++ch) {
        const int p0 = ch * 4;
        float tt[12];
        u32   cell[12];

        #pragma unroll
        for (int p = 0; p < 4; ++p) {
            const int pp = p0 + p;
            const float px = f[3*pp], py = f[3*pp+1], pz = f[3*pp+2];
            const float pxs = px + SHIFT, pys = py + SHIFT, pzs = pz + SHIFT;
            #pragma unroll
            for (int pl = 0; pl < NPLANES; ++pl) {
                const int k = p * 3 + pl;
                const float tk = (px*nx[pl] + py*ny[pl] + pz*nz[pl] + dd[pl]) * sc[pl];
                tt[k] = tk;
                const float qxs = fmaf(-tk, nx[pl], pxs);
                const float qys = fmaf(-tk, ny[pl], pys);
                const float qzs = fmaf(-tk, nz[pl], pzs);
                int ix = (int)fmaf(qxs, 32.0f, IOFF);
                int iy = (int)fmaf(qys, 32.0f, IOFF);
                int iz = (int)fmaf(qzs, 32.0f, IOFF);
                ix = min(max(ix, 0), RES - 1);
                iy = min(max(iy, 0), RES - 1);
                iz = min(max(iz, 0), RES - 1);
                const u32 gbyte = ((u32)ix << 12) + ((u32)iy << 7) + ((u32)iz << 2);
                cell[k] = *(const u32*)((const char*)tab + gbyte);
            }
        }

        #pragma unroll
        for (int p = 0; p < 4; ++p) {
            const int pp = p0 + p;
            const float pxs = f[3*pp] + SHIFT;
            const float pys = f[3*pp+1] + SHIFT;
            const float pzs = f[3*pp+2] + SHIFT;
            #pragma unroll
            for (int pl = 0; pl < NPLANES; ++pl) {
                const int k = p * 3 + pl;
                const u32 cl = cell[k];
                const float qxs = fmaf(-tt[k], nx[pl], pxs);
                const float qys = fmaf(-tt[k], ny[pl], pys);
                const float qzs = fmaf(-tt[k], nz[pl], pzs);
                const float dx = fmaf((float)(cl & 255u),         -INV255, qxs);
                const float dy = fmaf((float)((cl >> 8) & 255u),  -INV255, qys);
                const float dz = fmaf((float)((cl >> 16) & 255u), -INV255, qzs);
                const float w  = fmaf((float)(cl >> 24),          -INV255, 1.0f);
                acc = fmaf(__builtin_amdgcn_sqrtf(dx*dx + dy*dy + dz*dz), w, acc);
            }
        }
    }

    // ---- block reduce ----
    #pragma unroll
    for (int off = 32; off > 0; off >>= 1)
        acc += __shfl_down(acc, off);
    if ((t & 63) == 0) wsum[t >> 6] = acc;
    __syncthreads();
    if (t == 0) {
        float s = 0.0f;
        #pragma unroll
        for (int w = 0; w < NWAVES; ++w) s += wsum[w];
        part[blk] = s;
    }
}

// ---------------------------------------------------------------------------
// Kernel 3: finalize (proven R4 tail).
// ---------------------------------------------------------------------------
__global__ __launch_bounds__(256) void finalize_kernel(
    const float* __restrict__ part, int n_part,
    const float* __restrict__ planes,
    float* __restrict__ out)
{
    __shared__ float sdata[256];

    float s = 0.0f;
    for (int i = threadIdx.x; i < n_part; i += 256)
        s += part[i];

    float r = 0.0f;
    if (threadIdx.x < BATCH)
        r = reg_term(planes, threadIdx.x);

    float val = s * (1.0f / (float)BATCH) + r * (WREG_F / (float)BATCH);

    sdata[threadIdx.x] = val;
    __syncthreads();
    #pragma unroll
    for (int off = 128; off > 0; off >>= 1) {
        if (threadIdx.x < off) sdata[threadIdx.x] += sdata[threadIdx.x + off];
        __syncthreads();
    }
    if (threadIdx.x == 0) out[0] = sdata[0];
}

// ---------------------------------------------------------------------------
// Fallback (ws too small): direct fp32 gathers.
// ---------------------------------------------------------------------------
__global__ __launch_bounds__(256) void sym_fallback_kernel(
    const float* __restrict__ pc,
    const float* __restrict__ aux,
    const float* __restrict__ vox,
    const float* __restrict__ planes,
    float* __restrict__ part)
{
    const int chunk = swizzle_chunk(blockIdx.x);
    const int b  = chunk >> 5;
    const int cb = chunk & 31;

    float nx[3], ny[3], nz[3], dd[3], sc[3];
    #pragma unroll
    for (int pl = 0; pl < NPLANES; ++pl) {
        const float* P = planes + ((pl * BATCH + b) << 2);
        nx[pl] = P[0]; ny[pl] = P[1]; nz[pl] = P[2]; dd[pl] = P[3];
        sc[pl] = 2.0f / (nx[pl]*nx[pl] + ny[pl]*ny[pl] + nz[pl]*nz[pl]);
    }

    const int p0 = b * NPTS + cb * 1024 + threadIdx.x * 4;
    const f4* pc4 = (const f4*)pc + (size_t)(p0 >> 2) * 3;
    const f4 A  = __builtin_nontemporal_load(pc4 + 0);
    const f4 Bv = __builtin_nontemporal_load(pc4 + 1);
    const f4 C  = __builtin_nontemporal_load(pc4 + 2);

    const float px[4] = {A.x, A.w, Bv.z, C.y};
    const float py[4] = {A.y, Bv.x, Bv.w, C.z};
    const float pz[4] = {A.z, Bv.y, C.x, C.w};

    float acc = 0.0f;
    #pragma unroll
    for (int pt = 0; pt < 4; ++pt) {
        #pragma unroll
        for (int pl = 0; pl < NPLANES; ++pl) {
            const float tt = (px[pt]*nx[pl] + py[pt]*ny[pl] + pz[pt]*nz[pl]
                              + dd[pl]) * sc[pl];
            const float qx = px[pt] - tt * nx[pl];
            const float qy = py[pt] - tt * ny[pl];
            const float qz = pz[pt] - tt * nz[pl];
            int ix = (int)((qx + 0.5f) * (float)RES);
            int iy = (int)((qy + 0.5f) * (float)RES);
            int iz = (int)((qz + 0.5f) * (float)RES);
            ix = min(RES - 1, max(0, ix));
            iy = min(RES - 1, max(0, iy));
            iz = min(RES - 1, max(0, iz));
            const int gi = b * GCELLS + (ix << 10) + (iy << 5) + iz;
            const float v  = vox[gi];
            const float dx = qx - aux[gi*3+0] + EPS_PD;
            const float dy = qy - aux[gi*3+1] + EPS_PD;
            const float dz = qz - aux[gi*3+2] + EPS_PD;
            acc += sqrtf(dx*dx + dy*dy + dz*dz) * (1.0f - v);
        }
    }

    #pragma unroll
    for (int off = 32; off > 0; off >>= 1)
        acc += __shfl_down(acc, off);

    __shared__ float ws[4];
    if ((threadIdx.x & 63) == 0) ws[threadIdx.x >> 6] = acc;
    __syncthreads();
    if (threadIdx.x == 0)
        part[blockIdx.x] = ws[0] + ws[1] + ws[2] + ws[3];
}

// ---------------------------------------------------------------------------
extern "C" void kernel_launch(void* const* d_in, const int* in_sizes, int n_in,
                              void* d_out, int out_size, void* d_ws, size_t ws_size,
                              hipStream_t stream)
{
    const float* pc     = (const float*)d_in[0];
    const float* aux    = (const float*)d_in[1];
    const float* vox    = (const float*)d_in[2];
    const float* planes = (const float*)d_in[3];
    float* out = (float*)d_out;

    if (ws_size >= PACKED_BYTES + NB * sizeof(float)) {
        u32*   packed = (u32*)d_ws;
        float* part   = (float*)((char*)d_ws + PACKED_BYTES);
        pack_u8_kernel<<<PACK_BLOCKS, 256, 0, stream>>>(aux, vox, packed);
        sym_lds_kernel<<<NB, NT, 0, stream>>>(pc, packed, planes, part);
        finalize_kernel<<<1, 256, 0, stream>>>(part, NB, planes, out);
    } else {
        float* part = (float*)d_ws;
        sym_fallback_kernel<<<PACK_BLOCKS, 256, 0, stream>>>(pc, aux, vox, planes, part);
        finalize_kernel<<<1, 256, 0, stream>>>(part, PACK_BLOCKS, planes, out);
    }
}

// Round 10
// 34.760 us; speedup vs baseline: 6.1177x; 1.0363x over previous
//
#include <hip/hip_runtime.h>
#include <math.h>

#define RES     32
#define GCELLS  (RES * RES * RES)       // 32768
#define NPTS    32768
#define BATCH   64
#define NPLANES 3
#define EPS_PD  1e-6f
#define WREG_F  25.0f

#define NB      256                     // sym blocks: 1 per CU, 4 per batch
#define NT      1024
#define NWAVES  (NT / 64)

#define PACK_BLOCKS 2048
#define PACKED_BYTES ((size_t)BATCH * GCELLS * 4)    // 8 MiB u8x4 table
#define PART_OFF     PACKED_BYTES
#define CNT_OFF      (PACKED_BYTES + (size_t)NB * 4)
#define WS_NEED      (CNT_OFF + 4)

typedef float        f4 __attribute__((ext_vector_type(4)));
typedef unsigned int u32;
typedef u32          u4 __attribute__((ext_vector_type(4)));

// ---------------------------------------------------------------------------
// helpers
// ---------------------------------------------------------------------------
__device__ __forceinline__ u32 quant_cell(float x, float y, float z, float v) {
    const u32 ux = (u32)fmaf(x, 255.0f, 128.0f);   // round_half_up((c+0.5)*255)
    const u32 uy = (u32)fmaf(y, 255.0f, 128.0f);
    const u32 uz = (u32)fmaf(z, 255.0f, 128.0f);
    const u32 uv = (u32)fmaf(v, 255.0f, 0.5f);     // round(v*255)
    return ux | (uy << 8) | (uz << 16) | (uv << 24);
}

__device__ __forceinline__ float reg_term(const float* __restrict__ planes, int b) {
    float nv[3][3];
    #pragma unroll
    for (int p = 0; p < NPLANES; ++p) {
        const float nxv = planes[((p * BATCH + b) << 2) + 0];
        const float nyv = planes[((p * BATCH + b) << 2) + 1];
        const float nzv = planes[((p * BATCH + b) << 2) + 2];
        float nrm = fmaxf(sqrtf(nxv*nxv + nyv*nyv + nzv*nzv), 1e-12f);
        nv[p][0] = nxv / nrm; nv[p][1] = nyv / nrm; nv[p][2] = nzv / nrm;
    }
    float r = 0.0f;
    #pragma unroll
    for (int i = 0; i < 3; ++i)
        #pragma unroll
        for (int j = 0; j < 3; ++j) {
            const float m = nv[i][j] * nv[j][i] - (i == j ? 1.0f : 0.0f);
            r += m * m;
        }
    return r;
}

// ---------------------------------------------------------------------------
// Kernel 1: quantize (aux.xyz, vox) -> u8x4 table, XCD-swizzled so each
// XCD's L2 holds the 8 batch tables (1 MB) its sym blocks will stage.
// Also zeroes the completion counter for this call (published to sym by the
// kernel boundary -- no memset node needed, deterministic per replay).
// ---------------------------------------------------------------------------
__device__ __forceinline__ int swizzle_chunk(int bid) {
    return (bid & 7) * (PACK_BLOCKS / 8) + (bid >> 3);
}

__global__ __launch_bounds__(256) void pack_u8_kernel(
    const float* __restrict__ aux,
    const float* __restrict__ vox,
    u32* __restrict__ packed,
    u32* __restrict__ cnt)
{
    if (blockIdx.x == 0 && threadIdx.x == 0)
        __hip_atomic_store(cnt, 0u, __ATOMIC_RELAXED, __HIP_MEMORY_SCOPE_AGENT);

    const int chunk = swizzle_chunk(blockIdx.x);
    const int i = chunk * 256 + threadIdx.x;        // group of 4 cells

    const f4* a4 = (const f4*)aux + (size_t)i * 3;
    const f4 a = __builtin_nontemporal_load(a4 + 0);
    const f4 b = __builtin_nontemporal_load(a4 + 1);
    const f4 c = __builtin_nontemporal_load(a4 + 2);
    const f4 v = __builtin_nontemporal_load((const f4*)vox + i);

    u4 o;
    o[0] = quant_cell(a.x, a.y, a.z, v.x);
    o[1] = quant_cell(a.w, b.x, b.y, v.y);
    o[2] = quant_cell(b.z, b.w, c.x, v.z);
    o[3] = quant_cell(c.y, c.z, c.w, v.w);
    *((u4*)packed + i) = o;            // normal store: table stays in this L2
}

// ---------------------------------------------------------------------------
// Kernel 2: stage table to LDS; R4's compiler-interleaved gather loop
// (proven best); block reduce; LAST block (one atomic, no spinning) folds
// the final reduction + reg term -> out[0].
// ---------------------------------------------------------------------------
__global__ __launch_bounds__(NT, 4) void sym_lds_kernel(
    const float* __restrict__ pc,      // (B, N, 3)
    const u32* __restrict__ packed,    // (B*G) u8x4
    const float* __restrict__ planes,  // (3, B, 4)
    float* __restrict__ part,          // (NB)
    u32* __restrict__ cnt,             // (1), zeroed by pack kernel
    float* __restrict__ out)
{
    __shared__ u32   tab[GCELLS];      // 128 KiB
    __shared__ float wsum[NWAVES];
    __shared__ int   lastflag;

    const int t    = threadIdx.x;
    const int blk  = blockIdx.x;
    const int xcd  = blk & 7;
    const int slot = blk >> 3;
    const int b    = xcd * 8 + (slot >> 2);    // batch (same XCD as its packer)
    const int c    = slot & 3;                 // quarter of the batch's points

    // ---- pc loads first: HBM latency hides under table staging ----
    const f4* pc4 = (const f4*)pc
                  + (((size_t)(b * NPTS + c * 8192) * 3) >> 2)
                  + (size_t)t * 6;
    f4 A[6];
    #pragma unroll
    for (int i = 0; i < 6; ++i) A[i] = __builtin_nontemporal_load(pc4 + i);

    // ---- stage the batch table from L2 (8 x 16 B per thread, linear) ----
    const u4* gt = (const u4*)packed + (size_t)b * (GCELLS / 4);
    #pragma unroll
    for (int i = 0; i < 8; ++i) {
        const int k = i * NT + t;
        *(u4*)&tab[k * 4] = gt[k];
    }

    // ---- block-uniform plane constants ----
    float nx[3], ny[3], nz[3], dd[3], sc[3];
    #pragma unroll
    for (int pl = 0; pl < NPLANES; ++pl) {
        const float* P = planes + ((pl * BATCH + b) << 2);
        nx[pl] = P[0]; ny[pl] = P[1]; nz[pl] = P[2]; dd[pl] = P[3];
        sc[pl] = 2.0f / (nx[pl]*nx[pl] + ny[pl]*ny[pl] + nz[pl]*nz[pl]);
    }

    __syncthreads();

    const float* f = (const float*)A;
    const float SHIFT  = 0.5f + EPS_PD;        // fold +0.5 and +eps into q
    const float IOFF   = -32.0f * EPS_PD;      // undo eps in the index path
    const float INV255 = 1.0f / 255.0f;

    // ---- R4's gather loop: compiler-interleaved, 52 VGPR, proven ----
    float acc = 0.0f;
    #pragma unroll
    for (int p = 0; p < 8; ++p) {
        const float px = f[3*p], py = f[3*p+1], pz = f[3*p+2];
        const float pxs = px + SHIFT, pys = py + SHIFT, pzs = pz + SHIFT;
        #pragma unroll
        for (int pl = 0; pl < NPLANES; ++pl) {
            const float tt  = (px*nx[pl] + py*ny[pl] + pz*nz[pl] + dd[pl]) * sc[pl];
            const float qxs = fmaf(-tt, nx[pl], pxs);   // qx + 0.5 + eps
            const float qys = fmaf(-tt, ny[pl], pys);
            const float qzs = fmaf(-tt, nz[pl], pzs);
            int ix = (int)fmaf(qxs, 32.0f, IOFF);
            int iy = (int)fmaf(qys, 32.0f, IOFF);
            int iz = (int)fmaf(qzs, 32.0f, IOFF);
            ix = min(max(ix, 0), RES - 1);
            iy = min(max(iy, 0), RES - 1);
            iz = min(max(iz, 0), RES - 1);
            const u32 gbyte = ((u32)ix << 12) + ((u32)iy << 7) + ((u32)iz << 2);
            const u32 cell  = *(const u32*)((const char*)tab + gbyte);
            const float dx = fmaf((float)(cell & 255u),         -INV255, qxs);
            const float dy = fmaf((float)((cell >> 8) & 255u),  -INV255, qys);
            const float dz = fmaf((float)((cell >> 16) & 255u), -INV255, qzs);
            const float w  = fmaf((float)(cell >> 24),          -INV255, 1.0f);
            acc = fmaf(__builtin_amdgcn_sqrtf(dx*dx + dy*dy + dz*dz), w, acc);
        }
    }

    // ---- block reduce ----
    #pragma unroll
    for (int off = 32; off > 0; off >>= 1)
        acc += __shfl_down(acc, off);
    if ((t & 63) == 0) wsum[t >> 6] = acc;
    __syncthreads();
    if (t == 0) {
        float s = 0.0f;
        #pragma unroll
        for (int w = 0; w < NWAVES; ++w) s += wsum[w];
        // agent-scope release store so the last block sees it across XCDs
        __hip_atomic_store(&part[blk], s, __ATOMIC_RELEASE,
                           __HIP_MEMORY_SCOPE_AGENT);
        const u32 old = __hip_atomic_fetch_add(cnt, 1u, __ATOMIC_ACQ_REL,
                                               __HIP_MEMORY_SCOPE_AGENT);
        lastflag = (old == NB - 1) ? 1 : 0;
    }
    __syncthreads();

    // ---- last-arriving block: final reduction + reg term (no waiting) ----
    if (lastflag) {
        float val = 0.0f;
        if (t < NB)
            val = __hip_atomic_load(&part[t], __ATOMIC_ACQUIRE,
                                    __HIP_MEMORY_SCOPE_AGENT) * (1.0f / (float)BATCH);
        if (t < BATCH)
            val += reg_term(planes, t) * (WREG_F / (float)BATCH);

        #pragma unroll
        for (int off = 32; off > 0; off >>= 1)
            val += __shfl_down(val, off);
        if ((t & 63) == 0) wsum[t >> 6] = val;
        __syncthreads();
        if (t == 0) {
            float s = 0.0f;
            #pragma unroll
            for (int w = 0; w < NWAVES; ++w) s += wsum[w];
            out[0] = s;
        }
    }
}

// ---------------------------------------------------------------------------
// Fallback path (ws too small): direct fp32 gathers + separate finalize.
// ---------------------------------------------------------------------------
__global__ __launch_bounds__(256) void finalize_kernel(
    const float* __restrict__ part, int n_part,
    const float* __restrict__ planes,
    float* __restrict__ out)
{
    __shared__ float sdata[256];

    float s = 0.0f;
    for (int i = threadIdx.x; i < n_part; i += 256)
        s += part[i];

    float r = 0.0f;
    if (threadIdx.x < BATCH)
        r = reg_term(planes, threadIdx.x);

    float val = s * (1.0f / (float)BATCH) + r * (WREG_F / (float)BATCH);

    sdata[threadIdx.x] = val;
    __syncthreads();
    #pragma unroll
    for (int off = 128; off > 0; off >>= 1) {
        if (threadIdx.x < off) sdata[threadIdx.x] += sdata[threadIdx.x + off];
        __syncthreads();
    }
    if (threadIdx.x == 0) out[0] = sdata[0];
}

__global__ __launch_bounds__(256) void sym_fallback_kernel(
    const float* __restrict__ pc,
    const float* __restrict__ aux,
    const float* __restrict__ vox,
    const float* __restrict__ planes,
    float* __restrict__ part)
{
    const int chunk = swizzle_chunk(blockIdx.x);
    const int b  = chunk >> 5;
    const int cb = chunk & 31;

    float nx[3], ny[3], nz[3], dd[3], sc[3];
    #pragma unroll
    for (int pl = 0; pl < NPLANES; ++pl) {
        const float* P = planes + ((pl * BATCH + b) << 2);
        nx[pl] = P[0]; ny[pl] = P[1]; nz[pl] = P[2]; dd[pl] = P[3];
        sc[pl] = 2.0f / (nx[pl]*nx[pl] + ny[pl]*ny[pl] + nz[pl]*nz[pl]);
    }

    const int p0 = b * NPTS + cb * 1024 + threadIdx.x * 4;
    const f4* pc4 = (const f4*)pc + (size_t)(p0 >> 2) * 3;
    const f4 A  = __builtin_nontemporal_load(pc4 + 0);
    const f4 Bv = __builtin_nontemporal_load(pc4 + 1);
    const f4 C  = __builtin_nontemporal_load(pc4 + 2);

    const float px[4] = {A.x, A.w, Bv.z, C.y};
    const float py[4] = {A.y, Bv.x, Bv.w, C.z};
    const float pz[4] = {A.z, Bv.y, C.x, C.w};

    float acc = 0.0f;
    #pragma unroll
    for (int pt = 0; pt < 4; ++pt) {
        #pragma unroll
        for (int pl = 0; pl < NPLANES; ++pl) {
            const float tt = (px[pt]*nx[pl] + py[pt]*ny[pl] + pz[pt]*nz[pl]
                              + dd[pl]) * sc[pl];
            const float qx = px[pt] - tt * nx[pl];
            const float qy = py[pt] - tt * ny[pl];
            const float qz = pz[pt] - tt * nz[pl];
            int ix = (int)((qx + 0.5f) * (float)RES);
            int iy = (int)((qy + 0.5f) * (float)RES);
            int iz = (int)((qz + 0.5f) * (float)RES);
            ix = min(RES - 1, max(0, ix));
            iy = min(RES - 1, max(0, iy));
            iz = min(RES - 1, max(0, iz));
            const int gi = b * GCELLS + (ix << 10) + (iy << 5) + iz;
            const float v  = vox[gi];
            const float dx = qx - aux[gi*3+0] + EPS_PD;
            const float dy = qy - aux[gi*3+1] + EPS_PD;
            const float dz = qz - aux[gi*3+2] + EPS_PD;
            acc += sqrtf(dx*dx + dy*dy + dz*dz) * (1.0f - v);
        }
    }

    #pragma unroll
    for (int off = 32; off > 0; off >>= 1)
        acc += __shfl_down(acc, off);

    __shared__ float ws[4];
    if ((threadIdx.x & 63) == 0) ws[threadIdx.x >> 6] = acc;
    __syncthreads();
    if (threadIdx.x == 0)
        part[blockIdx.x] = ws[0] + ws[1] + ws[2] + ws[3];
}

// ---------------------------------------------------------------------------
extern "C" void kernel_launch(void* const* d_in, const int* in_sizes, int n_in,
                              void* d_out, int out_size, void* d_ws, size_t ws_size,
                              hipStream_t stream)
{
    const float* pc     = (const float*)d_in[0];
    const float* aux    = (const float*)d_in[1];
    const float* vox    = (const float*)d_in[2];
    const float* planes = (const float*)d_in[3];
    float* out = (float*)d_out;

    if (ws_size >= WS_NEED) {
        u32*   packed = (u32*)d_ws;
        float* part   = (float*)((char*)d_ws + PART_OFF);
        u32*   cnt    = (u32*)((char*)d_ws + CNT_OFF);
        pack_u8_kernel<<<PACK_BLOCKS, 256, 0, stream>>>(aux, vox, packed, cnt);
        sym_lds_kernel<<<NB, NT, 0, stream>>>(pc, packed, planes, part, cnt, out);
    } else {
        float* part = (float*)d_ws;
        sym_fallback_kernel<<<PACK_BLOCKS, 256, 0, stream>>>(pc, aux, vox, planes, part);
        finalize_kernel<<<1, 256, 0, stream>>>(part, PACK_BLOCKS, planes, out);
    }
}

// Round 11
// 26.897 us; speedup vs baseline: 7.9059x; 1.2923x over previous
//
#include <hip/hip_runtime.h>
#include <math.h>

#define RES     32
#define GCELLS  (RES * RES * RES)       // 32768
#define NPTS    32768
#define BATCH   64
#define NPLANES 3
#define EPS_PD  1e-6f
#define WREG_F  25.0f

#define NB      512                     // sym blocks: 2 per CU, 8 per batch
#define NT      1024
#define NWAVES  (NT / 64)

#define PACK_BLOCKS 2048
#define PACKED_BYTES ((size_t)BATCH * GCELLS * 2)    // 4 MiB u4x4 (u16/cell)

typedef float          f4 __attribute__((ext_vector_type(4)));
typedef unsigned int   u32;
typedef unsigned short u16;
typedef u32            u4 __attribute__((ext_vector_type(4)));
typedef u32            u2 __attribute__((ext_vector_type(2)));

// ---------------------------------------------------------------------------
// helpers
// ---------------------------------------------------------------------------
__device__ __forceinline__ u32 quant_cell4(float x, float y, float z, float v) {
    // 4-bit each: u = round_half_up((c+0.5)*15) = floor(c*15 + 8); v: round(v*15)
    const u32 ux = (u32)fmaf(x, 15.0f, 8.0f);
    const u32 uy = (u32)fmaf(y, 15.0f, 8.0f);
    const u32 uz = (u32)fmaf(z, 15.0f, 8.0f);
    const u32 uv = (u32)fmaf(v, 15.0f, 0.5f);
    return ux | (uy << 4) | (uz << 8) | (uv << 12);
}

__device__ __forceinline__ float reg_term(const float* __restrict__ planes, int b) {
    float nv[3][3];
    #pragma unroll
    for (int p = 0; p < NPLANES; ++p) {
        const float nxv = planes[((p * BATCH + b) << 2) + 0];
        const float nyv = planes[((p * BATCH + b) << 2) + 1];
        const float nzv = planes[((p * BATCH + b) << 2) + 2];
        float nrm = fmaxf(sqrtf(nxv*nxv + nyv*nyv + nzv*nzv), 1e-12f);
        nv[p][0] = nxv / nrm; nv[p][1] = nyv / nrm; nv[p][2] = nzv / nrm;
    }
    float r = 0.0f;
    #pragma unroll
    for (int i = 0; i < 3; ++i)
        #pragma unroll
        for (int j = 0; j < 3; ++j) {
            const float m = nv[i][j] * nv[j][i] - (i == j ? 1.0f : 0.0f);
            r += m * m;
        }
    return r;
}

// ---------------------------------------------------------------------------
// Kernel 1: quantize (aux.xyz, vox) -> u16 table (4 bits per field),
// XCD-swizzled so each XCD's L2 holds its 8 batch tables (512 KB).
// ---------------------------------------------------------------------------
__device__ __forceinline__ int swizzle_chunk(int bid) {
    return (bid & 7) * (PACK_BLOCKS / 8) + (bid >> 3);
}

__global__ __launch_bounds__(256) void pack_u16_kernel(
    const float* __restrict__ aux,
    const float* __restrict__ vox,
    u16* __restrict__ packed)
{
    const int chunk = swizzle_chunk(blockIdx.x);
    const int i = chunk * 256 + threadIdx.x;        // group of 4 cells

    const f4* a4 = (const f4*)aux + (size_t)i * 3;
    const f4 a = __builtin_nontemporal_load(a4 + 0);
    const f4 b = __builtin_nontemporal_load(a4 + 1);
    const f4 c = __builtin_nontemporal_load(a4 + 2);
    const f4 v = __builtin_nontemporal_load((const f4*)vox + i);

    const u32 c0 = quant_cell4(a.x, a.y, a.z, v.x);
    const u32 c1 = quant_cell4(a.w, b.x, b.y, v.y);
    const u32 c2 = quant_cell4(b.z, b.w, c.x, v.z);
    const u32 c3 = quant_cell4(c.y, c.z, c.w, v.w);

    u2 o;
    o[0] = c0 | (c1 << 16);
    o[1] = c2 | (c3 << 16);
    *((u2*)packed + i) = o;            // 8-B store: table stays in this L2
}

// ---------------------------------------------------------------------------
// Kernel 2: 512 blocks (2/CU, 32 waves/CU), 64 KB LDS table, 4 pts/thread,
// R4's proven compiler-interleaved gather loop.
// ---------------------------------------------------------------------------
__global__ __launch_bounds__(NT, 8) void sym_lds_kernel(
    const float* __restrict__ pc,      // (B, N, 3)
    const u16* __restrict__ packed,    // (B*G) u16
    const float* __restrict__ planes,  // (3, B, 4)
    float* __restrict__ part)          // (NB)
{
    __shared__ u16   tab[GCELLS];      // 64 KiB
    __shared__ float wsum[NWAVES];

    const int t    = threadIdx.x;
    const int blk  = blockIdx.x;
    const int xcd  = blk & 7;
    const int slot = blk >> 3;                 // 0..63 on this XCD
    const int b    = xcd * 8 + (slot >> 3);    // batch (8 blocks/batch, same XCD)
    const int c    = slot & 7;                 // eighth of the batch's points

    // ---- pc loads first: HBM latency hides under table staging ----
    const f4* pc4 = (const f4*)pc
                  + (((size_t)(b * NPTS + c * 4096) * 3) >> 2)
                  + (size_t)t * 3;
    f4 A[3];
    #pragma unroll
    for (int i = 0; i < 3; ++i) A[i] = __builtin_nontemporal_load(pc4 + i);

    // ---- stage the 64 KB batch table from L2 (4 x 16 B per thread) ----
    const u4* gt = (const u4*)packed + (size_t)b * (GCELLS / 8);
    #pragma unroll
    for (int i = 0; i < 4; ++i) {
        const int k = i * NT + t;
        *(u4*)&tab[k * 8] = gt[k];
    }

    // ---- block-uniform plane constants ----
    float nx[3], ny[3], nz[3], dd[3], sc[3];
    #pragma unroll
    for (int pl = 0; pl < NPLANES; ++pl) {
        const float* P = planes + ((pl * BATCH + b) << 2);
        nx[pl] = P[0]; ny[pl] = P[1]; nz[pl] = P[2]; dd[pl] = P[3];
        sc[pl] = 2.0f / (nx[pl]*nx[pl] + ny[pl]*ny[pl] + nz[pl]*nz[pl]);
    }

    __syncthreads();

    const float* f = (const float*)A;
    const float SHIFT = 0.5f + EPS_PD;         // fold +0.5 and +eps into q
    const float IOFF  = -32.0f * EPS_PD;       // undo eps in the index path
    const float INV15 = 1.0f / 15.0f;

    // ---- gather loop (R4 structure): 4 points x 3 planes ----
    float acc = 0.0f;
    #pragma unroll
    for (int p = 0; p < 4; ++p) {
        const float px = f[3*p], py = f[3*p+1], pz = f[3*p+2];
        const float pxs = px + SHIFT, pys = py + SHIFT, pzs = pz + SHIFT;
        #pragma unroll
        for (int pl = 0; pl < NPLANES; ++pl) {
            const float tt  = (px*nx[pl] + py*ny[pl] + pz*nz[pl] + dd[pl]) * sc[pl];
            const float qxs = fmaf(-tt, nx[pl], pxs);   // qx + 0.5 + eps
            const float qys = fmaf(-tt, ny[pl], pys);
            const float qzs = fmaf(-tt, nz[pl], pzs);
            int ix = (int)fmaf(qxs, 32.0f, IOFF);
            int iy = (int)fmaf(qys, 32.0f, IOFF);
            int iz = (int)fmaf(qzs, 32.0f, IOFF);
            ix = min(max(ix, 0), RES - 1);
            iy = min(max(iy, 0), RES - 1);
            iz = min(max(iz, 0), RES - 1);
            const u32 g    = ((u32)ix << 10) + ((u32)iy << 5) + (u32)iz;
            const u32 cell = (u32)tab[g];
            const float dx = fmaf((float)(cell & 15u),         -INV15, qxs);
            const float dy = fmaf((float)((cell >> 4) & 15u),  -INV15, qys);
            const float dz = fmaf((float)((cell >> 8) & 15u),  -INV15, qzs);
            const float w  = fmaf((float)(cell >> 12),         -INV15, 1.0f);
            acc = fmaf(__builtin_amdgcn_sqrtf(dx*dx + dy*dy + dz*dz), w, acc);
        }
    }

    // ---- block reduce ----
    #pragma unroll
    for (int off = 32; off > 0; off >>= 1)
        acc += __shfl_down(acc, off);
    if ((t & 63) == 0) wsum[t >> 6] = acc;
    __syncthreads();
    if (t == 0) {
        float s = 0.0f;
        #pragma unroll
        for (int w = 0; w < NWAVES; ++w) s += wsum[w];
        part[blk] = s;
    }
}

// ---------------------------------------------------------------------------
// Kernel 3: finalize (proven tail).
// ---------------------------------------------------------------------------
__global__ __launch_bounds__(256) void finalize_kernel(
    const float* __restrict__ part, int n_part,
    const float* __restrict__ planes,
    float* __restrict__ out)
{
    __shared__ float sdata[256];

    float s = 0.0f;
    for (int i = threadIdx.x; i < n_part; i += 256)
        s += part[i];

    float r = 0.0f;
    if (threadIdx.x < BATCH)
        r = reg_term(planes, threadIdx.x);

    float val = s * (1.0f / (float)BATCH) + r * (WREG_F / (float)BATCH);

    sdata[threadIdx.x] = val;
    __syncthreads();
    #pragma unroll
    for (int off = 128; off > 0; off >>= 1) {
        if (threadIdx.x < off) sdata[threadIdx.x] += sdata[threadIdx.x + off];
        __syncthreads();
    }
    if (threadIdx.x == 0) out[0] = sdata[0];
}

// ---------------------------------------------------------------------------
// Fallback (ws too small): direct fp32 gathers.
// ---------------------------------------------------------------------------
__global__ __launch_bounds__(256) void sym_fallback_kernel(
    const float* __restrict__ pc,
    const float* __restrict__ aux,
    const float* __restrict__ vox,
    const float* __restrict__ planes,
    float* __restrict__ part)
{
    const int chunk = swizzle_chunk(blockIdx.x);
    const int b  = chunk >> 5;
    const int cb = chunk & 31;

    float nx[3], ny[3], nz[3], dd[3], sc[3];
    #pragma unroll
    for (int pl = 0; pl < NPLANES; ++pl) {
        const float* P = planes + ((pl * BATCH + b) << 2);
        nx[pl] = P[0]; ny[pl] = P[1]; nz[pl] = P[2]; dd[pl] = P[3];
        sc[pl] = 2.0f / (nx[pl]*nx[pl] + ny[pl]*ny[pl] + nz[pl]*nz[pl]);
    }

    const int p0 = b * NPTS + cb * 1024 + threadIdx.x * 4;
    const f4* pc4 = (const f4*)pc + (size_t)(p0 >> 2) * 3;
    const f4 A  = __builtin_nontemporal_load(pc4 + 0);
    const f4 Bv = __builtin_nontemporal_load(pc4 + 1);
    const f4 C  = __builtin_nontemporal_load(pc4 + 2);

    const float px[4] = {A.x, A.w, Bv.z, C.y};
    const float py[4] = {A.y, Bv.x, Bv.w, C.z};
    const float pz[4] = {A.z, Bv.y, C.x, C.w};

    float acc = 0.0f;
    #pragma unroll
    for (int pt = 0; pt < 4; ++pt) {
        #pragma unroll
        for (int pl = 0; pl < NPLANES; ++pl) {
            const float tt = (px[pt]*nx[pl] + py[pt]*ny[pl] + pz[pt]*nz[pl]
                              + dd[pl]) * sc[pl];
            const float qx = px[pt] - tt * nx[pl];
            const float qy = py[pt] - tt * ny[pl];
            const float qz = pz[pt] - tt * nz[pl];
            int ix = (int)((qx + 0.5f) * (float)RES);
            int iy = (int)((qy + 0.5f) * (float)RES);
            int iz = (int)((qz + 0.5f) * (float)RES);
            ix = min(RES - 1, max(0, ix));
            iy = min(RES - 1, max(0, iy));
            iz = min(RES - 1, max(0, iz));
            const int gi = b * GCELLS + (ix << 10) + (iy << 5) + iz;
            const float v  = vox[gi];
            const float dx = qx - aux[gi*3+0] + EPS_PD;
            const float dy = qy - aux[gi*3+1] + EPS_PD;
            const float dz = qz - aux[gi*3+2] + EPS_PD;
            acc += sqrtf(dx*dx + dy*dy + dz*dz) * (1.0f - v);
        }
    }

    #pragma unroll
    for (int off = 32; off > 0; off >>= 1)
        acc += __shfl_down(acc, off);

    __shared__ float ws[4];
    if ((threadIdx.x & 63) == 0) ws[threadIdx.x >> 6] = acc;
    __syncthreads();
    if (threadIdx.x == 0)
        part[blockIdx.x] = ws[0] + ws[1] + ws[2] + ws[3];
}

// ---------------------------------------------------------------------------
extern "C" void kernel_launch(void* const* d_in, const int* in_sizes, int n_in,
                              void* d_out, int out_size, void* d_ws, size_t ws_size,
                              hipStream_t stream)
{
    const float* pc     = (const float*)d_in[0];
    const float* aux    = (const float*)d_in[1];
    const float* vox    = (const float*)d_in[2];
    const float* planes = (const float*)d_in[3];
    float* out = (float*)d_out;

    if (ws_size >= PACKED_BYTES + NB * sizeof(float)) {
        u16*   packed = (u16*)d_ws;
        float* part   = (float*)((char*)d_ws + PACKED_BYTES);
        pack_u16_kernel<<<PACK_BLOCKS, 256, 0, stream>>>(aux, vox, packed);
        sym_lds_kernel<<<NB, NT, 0, stream>>>(pc, packed, planes, part);
        finalize_kernel<<<1, 256, 0, stream>>>(part, NB, planes, out);
    } else {
        float* part = (float*)d_ws;
        sym_fallback_kernel<<<PACK_BLOCKS, 256, 0, stream>>>(pc, aux, vox, planes, part);
        finalize_kernel<<<1, 256, 0, stream>>>(part, PACK_BLOCKS, planes, out);
    }
}

// Round 12
// 26.356 us; speedup vs baseline: 8.0682x; 1.0205x over previous
//
#include <hip/hip_runtime.h>
#include <math.h>

#define RES     32
#define GCELLS  (RES * RES * RES)       // 32768
#define NPTS    32768
#define BATCH   64
#define NPLANES 3
#define EPS_PD  1e-6f
#define WREG_F  25.0f

#define NB      512                     // sym blocks: 2 per CU (32 waves = max)
#define NT      1024
#define NWAVES  (NT / 64)

#define PACK_BLOCKS 2048
#define PACKED_BYTES ((size_t)BATCH * GCELLS * 2)    // 4 MiB (u16/cell)

typedef float          f4 __attribute__((ext_vector_type(4)));
typedef unsigned int   u32;
typedef unsigned short u16;
typedef u32            u4 __attribute__((ext_vector_type(4)));
typedef u32            u2 __attribute__((ext_vector_type(2)));

// ---------------------------------------------------------------------------
// helpers
// ---------------------------------------------------------------------------
__device__ __forceinline__ u32 quant_cell4(float x, float y, float z, float v) {
    // 4-bit each: u = round_half_up((c+0.5)*15) = floor(c*15 + 8); v: round(v*15)
    const u32 ux = (u32)fmaf(x, 15.0f, 8.0f);
    const u32 uy = (u32)fmaf(y, 15.0f, 8.0f);
    const u32 uz = (u32)fmaf(z, 15.0f, 8.0f);
    const u32 uv = (u32)fmaf(v, 15.0f, 0.5f);
    return ux | (uy << 4) | (uz << 8) | (uv << 12);
}

__device__ __forceinline__ float reg_term(const float* __restrict__ planes, int b) {
    float nv[3][3];
    #pragma unroll
    for (int p = 0; p < NPLANES; ++p) {
        const float nxv = planes[((p * BATCH + b) << 2) + 0];
        const float nyv = planes[((p * BATCH + b) << 2) + 1];
        const float nzv = planes[((p * BATCH + b) << 2) + 2];
        float nrm = fmaxf(sqrtf(nxv*nxv + nyv*nyv + nzv*nzv), 1e-12f);
        nv[p][0] = nxv / nrm; nv[p][1] = nyv / nrm; nv[p][2] = nzv / nrm;
    }
    float r = 0.0f;
    #pragma unroll
    for (int i = 0; i < 3; ++i)
        #pragma unroll
        for (int j = 0; j < 3; ++j) {
            const float m = nv[i][j] * nv[j][i] - (i == j ? 1.0f : 0.0f);
            r += m * m;
        }
    return r;
}

// ---------------------------------------------------------------------------
// Kernel 1: quantize (aux.xyz, vox) -> u16 table (4 bits/field), XCD-swizzled
// so each XCD's L2 holds its 8 batch tables (512 KB).
// ---------------------------------------------------------------------------
__device__ __forceinline__ int swizzle_chunk(int bid) {
    return (bid & 7) * (PACK_BLOCKS / 8) + (bid >> 3);
}

__global__ __launch_bounds__(256) void pack_u16_kernel(
    const float* __restrict__ aux,
    const float* __restrict__ vox,
    u16* __restrict__ packed)
{
    const int chunk = swizzle_chunk(blockIdx.x);
    const int i = chunk * 256 + threadIdx.x;        // group of 4 cells

    const f4* a4 = (const f4*)aux + (size_t)i * 3;
    const f4 a = __builtin_nontemporal_load(a4 + 0);
    const f4 b = __builtin_nontemporal_load(a4 + 1);
    const f4 c = __builtin_nontemporal_load(a4 + 2);
    const f4 v = __builtin_nontemporal_load((const f4*)vox + i);

    const u32 c0 = quant_cell4(a.x, a.y, a.z, v.x);
    const u32 c1 = quant_cell4(a.w, b.x, b.y, v.y);
    const u32 c2 = quant_cell4(b.z, b.w, c.x, v.z);
    const u32 c3 = quant_cell4(c.y, c.z, c.w, v.w);

    u2 o;
    o[0] = c0 | (c1 << 16);
    o[1] = c2 | (c3 << 16);
    *((u2*)packed + i) = o;            // 8-B store: table stays in this L2
}

// ---------------------------------------------------------------------------
// Kernel 2: 512 blocks (2/CU = 32 waves/CU, HW max), 64 KB LDS table staged
// conflict-free (b32 stride-1), 4 pts/thread, compiler-interleaved gather.
// ---------------------------------------------------------------------------
__global__ __launch_bounds__(NT, 8) void sym_lds_kernel(
    const float* __restrict__ pc,      // (B, N, 3)
    const u16* __restrict__ packed,    // (B*G) u16
    const float* __restrict__ planes,  // (3, B, 4)
    float* __restrict__ part)          // (NB)
{
    __shared__ u16   tab[GCELLS];      // 64 KiB
    __shared__ float wsum[NWAVES];

    const int t    = threadIdx.x;
    const int blk  = blockIdx.x;
    const int xcd  = blk & 7;
    const int slot = blk >> 3;                 // 0..63 on this XCD
    const int b    = xcd * 8 + (slot >> 3);    // batch (8 blocks/batch, same XCD)
    const int c    = slot & 7;                 // eighth of the batch's points

    // ---- pc loads first: HBM latency hides under table staging ----
    const f4* pc4 = (const f4*)pc
                  + (((size_t)(b * NPTS + c * 4096) * 3) >> 2)
                  + (size_t)t * 3;
    f4 A[3];
    #pragma unroll
    for (int i = 0; i < 3; ++i) A[i] = __builtin_nontemporal_load(pc4 + i);

    // ---- stage 64 KB table: 16 x (dword load + b32 LDS write), 4 B/lane
    //      stride -> consecutive banks -> conflict-free ----
    const u32* gt32  = (const u32*)packed + (size_t)b * (GCELLS / 2);
    u32*       tab32 = (u32*)tab;
    #pragma unroll
    for (int i = 0; i < 16; ++i) {
        const int k = i * NT + t;
        tab32[k] = gt32[k];
    }

    // ---- block-uniform plane constants (sc folded into normals) ----
    float nx[3], ny[3], nz[3], dd[3], mx[3], my[3], mz[3];
    #pragma unroll
    for (int pl = 0; pl < NPLANES; ++pl) {
        const float* P = planes + ((pl * BATCH + b) << 2);
        nx[pl] = P[0]; ny[pl] = P[1]; nz[pl] = P[2]; dd[pl] = P[3];
        const float sc = 2.0f / (nx[pl]*nx[pl] + ny[pl]*ny[pl] + nz[pl]*nz[pl]);
        mx[pl] = sc * nx[pl]; my[pl] = sc * ny[pl]; mz[pl] = sc * nz[pl];
    }

    __syncthreads();

    const float* f = (const float*)A;
    const float SHIFT = 0.5f + EPS_PD;         // fold +0.5 and +eps into q
    const float IOFF  = -32.0f * EPS_PD;       // undo eps in the index path
    const float INV15 = 1.0f / 15.0f;

    // ---- gather loop: 4 points x 3 planes, compiler-interleaved ----
    float acc = 0.0f;
    #pragma unroll
    for (int p = 0; p < 4; ++p) {
        const float px = f[3*p], py = f[3*p+1], pz = f[3*p+2];
        const float pxs = px + SHIFT, pys = py + SHIFT, pzs = pz + SHIFT;
        #pragma unroll
        for (int pl = 0; pl < NPLANES; ++pl) {
            // tt' = dot(p,n) + d  (3 fma); q = p - tt' * (sc*n)
            const float tt  = fmaf(pz, nz[pl], fmaf(py, ny[pl],
                              fmaf(px, nx[pl], dd[pl])));
            const float qxs = fmaf(-tt, mx[pl], pxs);   // qx + 0.5 + eps
            const float qys = fmaf(-tt, my[pl], pys);
            const float qzs = fmaf(-tt, mz[pl], pzs);
            int ix = (int)fmaf(qxs, 32.0f, IOFF);
            int iy = (int)fmaf(qys, 32.0f, IOFF);
            int iz = (int)fmaf(qzs, 32.0f, IOFF);
            ix = min(max(ix, 0), RES - 1);
            iy = min(max(iy, 0), RES - 1);
            iz = min(max(iz, 0), RES - 1);
            const u32 g    = ((u32)ix << 10) + ((u32)iy << 5) + (u32)iz;
            const u32 cell = (u32)tab[g];
            const float dx = fmaf((float)(cell & 15u),        -INV15, qxs);
            const float dy = fmaf((float)((cell >> 4) & 15u), -INV15, qys);
            const float dz = fmaf((float)((cell >> 8) & 15u), -INV15, qzs);
            const float w  = fmaf((float)(cell >> 12),        -INV15, 1.0f);
            acc = fmaf(__builtin_amdgcn_sqrtf(dx*dx + dy*dy + dz*dz), w, acc);
        }
    }

    // ---- block reduce ----
    #pragma unroll
    for (int off = 32; off > 0; off >>= 1)
        acc += __shfl_down(acc, off);
    if ((t & 63) == 0) wsum[t >> 6] = acc;
    __syncthreads();
    if (t == 0) {
        float s = 0.0f;
        #pragma unroll
        for (int w = 0; w < NWAVES; ++w) s += wsum[w];
        part[blk] = s;
    }
}

// ---------------------------------------------------------------------------
// Kernel 3: finalize — 512 threads, one part element each + reg term.
// ---------------------------------------------------------------------------
__global__ __launch_bounds__(512) void finalize_kernel(
    const float* __restrict__ part,
    const float* __restrict__ planes,
    float* __restrict__ out)
{
    __shared__ float wsum[8];
    const int t = threadIdx.x;

    float val = part[t] * (1.0f / (float)BATCH);
    if (t < BATCH)
        val += reg_term(planes, t) * (WREG_F / (float)BATCH);

    #pragma unroll
    for (int off = 32; off > 0; off >>= 1)
        val += __shfl_down(val, off);
    if ((t & 63) == 0) wsum[t >> 6] = val;
    __syncthreads();
    if (t == 0) {
        float s = 0.0f;
        #pragma unroll
        for (int w = 0; w < 8; ++w) s += wsum[w];
        out[0] = s;
    }
}

// ---------------------------------------------------------------------------
// Fallback (ws too small): direct fp32 gathers + generic finalize.
// ---------------------------------------------------------------------------
__global__ __launch_bounds__(256) void finalize_fb_kernel(
    const float* __restrict__ part, int n_part,
    const float* __restrict__ planes,
    float* __restrict__ out)
{
    __shared__ float sdata[256];

    float s = 0.0f;
    for (int i = threadIdx.x; i < n_part; i += 256)
        s += part[i];

    float r = 0.0f;
    if (threadIdx.x < BATCH)
        r = reg_term(planes, threadIdx.x);

    float val = s * (1.0f / (float)BATCH) + r * (WREG_F / (float)BATCH);

    sdata[threadIdx.x] = val;
    __syncthreads();
    #pragma unroll
    for (int off = 128; off > 0; off >>= 1) {
        if (threadIdx.x < off) sdata[threadIdx.x] += sdata[threadIdx.x + off];
        __syncthreads();
    }
    if (threadIdx.x == 0) out[0] = sdata[0];
}

__global__ __launch_bounds__(256) void sym_fallback_kernel(
    const float* __restrict__ pc,
    const float* __restrict__ aux,
    const float* __restrict__ vox,
    const float* __restrict__ planes,
    float* __restrict__ part)
{
    const int chunk = swizzle_chunk(blockIdx.x);
    const int b  = chunk >> 5;
    const int cb = chunk & 31;

    float nx[3], ny[3], nz[3], dd[3], sc[3];
    #pragma unroll
    for (int pl = 0; pl < NPLANES; ++pl) {
        const float* P = planes + ((pl * BATCH + b) << 2);
        nx[pl] = P[0]; ny[pl] = P[1]; nz[pl] = P[2]; dd[pl] = P[3];
        sc[pl] = 2.0f / (nx[pl]*nx[pl] + ny[pl]*ny[pl] + nz[pl]*nz[pl]);
    }

    const int p0 = b * NPTS + cb * 1024 + threadIdx.x * 4;
    const f4* pc4 = (const f4*)pc + (size_t)(p0 >> 2) * 3;
    const f4 A  = __builtin_nontemporal_load(pc4 + 0);
    const f4 Bv = __builtin_nontemporal_load(pc4 + 1);
    const f4 C  = __builtin_nontemporal_load(pc4 + 2);

    const float px[4] = {A.x, A.w, Bv.z, C.y};
    const float py[4] = {A.y, Bv.x, Bv.w, C.z};
    const float pz[4] = {A.z, Bv.y, C.x, C.w};

    float acc = 0.0f;
    #pragma unroll
    for (int pt = 0; pt < 4; ++pt) {
        #pragma unroll
        for (int pl = 0; pl < NPLANES; ++pl) {
            const float tt = (px[pt]*nx[pl] + py[pt]*ny[pl] + pz[pt]*nz[pl]
                              + dd[pl]) * sc[pl];
            const float qx = px[pt] - tt * nx[pl];
            const float qy = py[pt] - tt * ny[pl];
            const float qz = pz[pt] - tt * nz[pl];
            int ix = (int)((qx + 0.5f) * (float)RES);
            int iy = (int)((qy + 0.5f) * (float)RES);
            int iz = (int)((qz + 0.5f) * (float)RES);
            ix = min(RES - 1, max(0, ix));
            iy = min(RES - 1, max(0, iy));
            iz = min(RES - 1, max(0, iz));
            const int gi = b * GCELLS + (ix << 10) + (iy << 5) + iz;
            const float v  = vox[gi];
            const float dx = qx - aux[gi*3+0] + EPS_PD;
            const float dy = qy - aux[gi*3+1] + EPS_PD;
            const float dz = qz - aux[gi*3+2] + EPS_PD;
            acc += sqrtf(dx*dx + dy*dy + dz*dz) * (1.0f - v);
        }
    }

    #pragma unroll
    for (int off = 32; off > 0; off >>= 1)
        acc += __shfl_down(acc, off);

    __shared__ float ws[4];
    if ((threadIdx.x & 63) == 0) ws[threadIdx.x >> 6] = acc;
    __syncthreads();
    if (threadIdx.x == 0)
        part[blockIdx.x] = ws[0] + ws[1] + ws[2] + ws[3];
}

// ---------------------------------------------------------------------------
extern "C" void kernel_launch(void* const* d_in, const int* in_sizes, int n_in,
                              void* d_out, int out_size, void* d_ws, size_t ws_size,
                              hipStream_t stream)
{
    const float* pc     = (const float*)d_in[0];
    const float* aux    = (const float*)d_in[1];
    const float* vox    = (const float*)d_in[2];
    const float* planes = (const float*)d_in[3];
    float* out = (float*)d_out;

    if (ws_size >= PACKED_BYTES + NB * sizeof(float)) {
        u16*   packed = (u16*)d_ws;
        float* part   = (float*)((char*)d_ws + PACKED_BYTES);
        pack_u16_kernel<<<PACK_BLOCKS, 256, 0, stream>>>(aux, vox, packed);
        sym_lds_kernel<<<NB, NT, 0, stream>>>(pc, packed, planes, part);
        finalize_kernel<<<1, 512, 0, stream>>>(part, planes, out);
    } else {
        float* part = (float*)d_ws;
        sym_fallback_kernel<<<PACK_BLOCKS, 256, 0, stream>>>(pc, aux, vox, planes, part);
        finalize_fb_kernel<<<1, 256, 0, stream>>>(part, PACK_BLOCKS, planes, out);
    }
}

// Round 13
// 24.203 us; speedup vs baseline: 8.7859x; 1.0890x over previous
//
#include <hip/hip_runtime.h>
#include <math.h>

#define RES     32
#define GCELLS  (RES * RES * RES)       // 32768
#define NPTS    32768
#define BATCH   64
#define NPLANES 3
#define EPS_PD  1e-6f
#define WREG_F  25.0f

#define NB      512                     // sym blocks: 2 per CU (32 waves = max)
#define NT      1024
#define NWAVES  (NT / 64)

#define PACK_BLOCKS 2048
#define PACKED_BYTES ((size_t)BATCH * GCELLS * 2)    // 4 MiB (u16/cell)

typedef float          f4 __attribute__((ext_vector_type(4)));
typedef unsigned int   u32;
typedef unsigned short u16;
typedef u32            u4 __attribute__((ext_vector_type(4)));
typedef u32            u2 __attribute__((ext_vector_type(2)));

// ---------------------------------------------------------------------------
// helpers
// ---------------------------------------------------------------------------
__device__ __forceinline__ u32 quant_cell4(float x, float y, float z, float v) {
    // 4-bit each: u = round_half_up((c+0.5)*15) = floor(c*15 + 8); v: round(v*15)
    const u32 ux = (u32)fmaf(x, 15.0f, 8.0f);
    const u32 uy = (u32)fmaf(y, 15.0f, 8.0f);
    const u32 uz = (u32)fmaf(z, 15.0f, 8.0f);
    const u32 uv = (u32)fmaf(v, 15.0f, 0.5f);
    return ux | (uy << 4) | (uz << 8) | (uv << 12);
}

__device__ __forceinline__ float reg_term(const float* __restrict__ planes, int b) {
    float nv[3][3];
    #pragma unroll
    for (int p = 0; p < NPLANES; ++p) {
        const float nxv = planes[((p * BATCH + b) << 2) + 0];
        const float nyv = planes[((p * BATCH + b) << 2) + 1];
        const float nzv = planes[((p * BATCH + b) << 2) + 2];
        float nrm = fmaxf(sqrtf(nxv*nxv + nyv*nyv + nzv*nzv), 1e-12f);
        nv[p][0] = nxv / nrm; nv[p][1] = nyv / nrm; nv[p][2] = nzv / nrm;
    }
    float r = 0.0f;
    #pragma unroll
    for (int i = 0; i < 3; ++i)
        #pragma unroll
        for (int j = 0; j < 3; ++j) {
            const float m = nv[i][j] * nv[j][i] - (i == j ? 1.0f : 0.0f);
            r += m * m;
        }
    return r;
}

// ---------------------------------------------------------------------------
// Kernel 1: quantize (aux.xyz, vox) -> u16 table (4 bits/field), XCD-swizzled
// so each XCD's L2 holds its 8 batch tables (512 KB). Plain loads: let the
// inputs settle into L3 so graph replays read at L3 bandwidth, not HBM.
// ---------------------------------------------------------------------------
__device__ __forceinline__ int swizzle_chunk(int bid) {
    return (bid & 7) * (PACK_BLOCKS / 8) + (bid >> 3);
}

__global__ __launch_bounds__(256) void pack_u16_kernel(
    const float* __restrict__ aux,
    const float* __restrict__ vox,
    u16* __restrict__ packed)
{
    const int chunk = swizzle_chunk(blockIdx.x);
    const int i = chunk * 256 + threadIdx.x;        // group of 4 cells

    const f4* a4 = (const f4*)aux + (size_t)i * 3;
    const f4 a = a4[0];
    const f4 b = a4[1];
    const f4 c = a4[2];
    const f4 v = ((const f4*)vox)[i];

    const u32 c0 = quant_cell4(a.x, a.y, a.z, v.x);
    const u32 c1 = quant_cell4(a.w, b.x, b.y, v.y);
    const u32 c2 = quant_cell4(b.z, b.w, c.x, v.z);
    const u32 c3 = quant_cell4(c.y, c.z, c.w, v.w);

    u2 o;
    o[0] = c0 | (c1 << 16);
    o[1] = c2 | (c3 << 16);
    *((u2*)packed + i) = o;            // 8-B store: table stays in this L2
}

// ---------------------------------------------------------------------------
// Kernel 2: 512 blocks (2/CU = 32 waves/CU, HW max), 64 KB LDS table staged
// conflict-free (b32 stride-1), 4 pts/thread, compiler-interleaved gather.
// ---------------------------------------------------------------------------
__global__ __launch_bounds__(NT, 8) void sym_lds_kernel(
    const float* __restrict__ pc,      // (B, N, 3)
    const u16* __restrict__ packed,    // (B*G) u16
    const float* __restrict__ planes,  // (3, B, 4)
    float* __restrict__ part)          // (NB)
{
    __shared__ u16   tab[GCELLS];      // 64 KiB
    __shared__ float wsum[NWAVES];

    const int t    = threadIdx.x;
    const int blk  = blockIdx.x;
    const int xcd  = blk & 7;
    const int slot = blk >> 3;                 // 0..63 on this XCD
    const int b    = xcd * 8 + (slot >> 3);    // batch (8 blocks/batch, same XCD)
    const int c    = slot & 7;                 // eighth of the batch's points

    // ---- pc loads first: latency hides under table staging ----
    const f4* pc4 = (const f4*)pc
                  + (((size_t)(b * NPTS + c * 4096) * 3) >> 2)
                  + (size_t)t * 3;
    f4 A[3];
    #pragma unroll
    for (int i = 0; i < 3; ++i) A[i] = pc4[i];

    // ---- stage 64 KB table: 16 x (dword load + b32 LDS write), 4 B/lane
    //      stride -> consecutive banks -> conflict-free ----
    const u32* gt32  = (const u32*)packed + (size_t)b * (GCELLS / 2);
    u32*       tab32 = (u32*)tab;
    #pragma unroll
    for (int i = 0; i < 16; ++i) {
        const int k = i * NT + t;
        tab32[k] = gt32[k];
    }

    // ---- block-uniform plane constants (sc folded into normals) ----
    float nx[3], ny[3], nz[3], dd[3], mx[3], my[3], mz[3];
    #pragma unroll
    for (int pl = 0; pl < NPLANES; ++pl) {
        const float* P = planes + ((pl * BATCH + b) << 2);
        nx[pl] = P[0]; ny[pl] = P[1]; nz[pl] = P[2]; dd[pl] = P[3];
        const float sc = 2.0f / (nx[pl]*nx[pl] + ny[pl]*ny[pl] + nz[pl]*nz[pl]);
        mx[pl] = sc * nx[pl]; my[pl] = sc * ny[pl]; mz[pl] = sc * nz[pl];
    }

    __syncthreads();

    const float* f = (const float*)A;
    const float SHIFT = 0.5f + EPS_PD;         // fold +0.5 and +eps into q
    const float IOFF  = -32.0f * EPS_PD;       // undo eps in the index path
    const float INV15 = 1.0f / 15.0f;

    // ---- gather loop: 4 points x 3 planes, compiler-interleaved ----
    float acc = 0.0f;
    #pragma unroll
    for (int p = 0; p < 4; ++p) {
        const float px = f[3*p], py = f[3*p+1], pz = f[3*p+2];
        const float pxs = px + SHIFT, pys = py + SHIFT, pzs = pz + SHIFT;
        #pragma unroll
        for (int pl = 0; pl < NPLANES; ++pl) {
            // tt' = dot(p,n) + d  (3 fma); q = p - tt' * (sc*n)
            const float tt  = fmaf(pz, nz[pl], fmaf(py, ny[pl],
                              fmaf(px, nx[pl], dd[pl])));
            const float qxs = fmaf(-tt, mx[pl], pxs);   // qx + 0.5 + eps
            const float qys = fmaf(-tt, my[pl], pys);
            const float qzs = fmaf(-tt, mz[pl], pzs);
            int ix = (int)fmaf(qxs, 32.0f, IOFF);
            int iy = (int)fmaf(qys, 32.0f, IOFF);
            int iz = (int)fmaf(qzs, 32.0f, IOFF);
            ix = min(max(ix, 0), RES - 1);
            iy = min(max(iy, 0), RES - 1);
            iz = min(max(iz, 0), RES - 1);
            const u32 g    = ((u32)ix << 10) + ((u32)iy << 5) + (u32)iz;
            const u32 cell = (u32)tab[g];
            const float dx = fmaf((float)(cell & 15u),        -INV15, qxs);
            const float dy = fmaf((float)((cell >> 4) & 15u), -INV15, qys);
            const float dz = fmaf((float)((cell >> 8) & 15u), -INV15, qzs);
            const float w  = fmaf((float)(cell >> 12),        -INV15, 1.0f);
            acc = fmaf(__builtin_amdgcn_sqrtf(dx*dx + dy*dy + dz*dz), w, acc);
        }
    }

    // ---- block reduce ----
    #pragma unroll
    for (int off = 32; off > 0; off >>= 1)
        acc += __shfl_down(acc, off);
    if ((t & 63) == 0) wsum[t >> 6] = acc;
    __syncthreads();
    if (t == 0) {
        float s = 0.0f;
        #pragma unroll
        for (int w = 0; w < NWAVES; ++w) s += wsum[w];
        part[blk] = s;
    }
}

// ---------------------------------------------------------------------------
// Kernel 3: finalize — 512 threads, one part element each + reg term.
// ---------------------------------------------------------------------------
__global__ __launch_bounds__(512) void finalize_kernel(
    const float* __restrict__ part,
    const float* __restrict__ planes,
    float* __restrict__ out)
{
    __shared__ float wsum[8];
    const int t = threadIdx.x;

    float val = part[t] * (1.0f / (float)BATCH);
    if (t < BATCH)
        val += reg_term(planes, t) * (WREG_F / (float)BATCH);

    #pragma unroll
    for (int off = 32; off > 0; off >>= 1)
        val += __shfl_down(val, off);
    if ((t & 63) == 0) wsum[t >> 6] = val;
    __syncthreads();
    if (t == 0) {
        float s = 0.0f;
        #pragma unroll
        for (int w = 0; w < 8; ++w) s += wsum[w];
        out[0] = s;
    }
}

// ---------------------------------------------------------------------------
// Fallback (ws too small): direct fp32 gathers + generic finalize.
// ---------------------------------------------------------------------------
__global__ __launch_bounds__(256) void finalize_fb_kernel(
    const float* __restrict__ part, int n_part,
    const float* __restrict__ planes,
    float* __restrict__ out)
{
    __shared__ float sdata[256];

    float s = 0.0f;
    for (int i = threadIdx.x; i < n_part; i += 256)
        s += part[i];

    float r = 0.0f;
    if (threadIdx.x < BATCH)
        r = reg_term(planes, threadIdx.x);

    float val = s * (1.0f / (float)BATCH) + r * (WREG_F / (float)BATCH);

    sdata[threadIdx.x] = val;
    __syncthreads();
    #pragma unroll
    for (int off = 128; off > 0; off >>= 1) {
        if (threadIdx.x < off) sdata[threadIdx.x] += sdata[threadIdx.x + off];
        __syncthreads();
    }
    if (threadIdx.x == 0) out[0] = sdata[0];
}

__global__ __launch_bounds__(256) void sym_fallback_kernel(
    const float* __restrict__ pc,
    const float* __restrict__ aux,
    const float* __restrict__ vox,
    const float* __restrict__ planes,
    float* __restrict__ part)
{
    const int chunk = swizzle_chunk(blockIdx.x);
    const int b  = chunk >> 5;
    const int cb = chunk & 31;

    float nx[3], ny[3], nz[3], dd[3], sc[3];
    #pragma unroll
    for (int pl = 0; pl < NPLANES; ++pl) {
        const float* P = planes + ((pl * BATCH + b) << 2);
        nx[pl] = P[0]; ny[pl] = P[1]; nz[pl] = P[2]; dd[pl] = P[3];
        sc[pl] = 2.0f / (nx[pl]*nx[pl] + ny[pl]*ny[pl] + nz[pl]*nz[pl]);
    }

    const int p0 = b * NPTS + cb * 1024 + threadIdx.x * 4;
    const f4* pc4 = (const f4*)pc + (size_t)(p0 >> 2) * 3;
    const f4 A  = pc4[0];
    const f4 Bv = pc4[1];
    const f4 C  = pc4[2];

    const float px[4] = {A.x, A.w, Bv.z, C.y};
    const float py[4] = {A.y, Bv.x, Bv.w, C.z};
    const float pz[4] = {A.z, Bv.y, C.x, C.w};

    float acc = 0.0f;
    #pragma unroll
    for (int pt = 0; pt < 4; ++pt) {
        #pragma unroll
        for (int pl = 0; pl < NPLANES; ++pl) {
            const float tt = (px[pt]*nx[pl] + py[pt]*ny[pl] + pz[pt]*nz[pl]
                              + dd[pl]) * sc[pl];
            const float qx = px[pt] - tt * nx[pl];
            const float qy = py[pt] - tt * ny[pl];
            const float qz = pz[pt] - tt * nz[pl];
            int ix = (int)((qx + 0.5f) * (float)RES);
            int iy = (int)((qy + 0.5f) * (float)RES);
            int iz = (int)((qz + 0.5f) * (float)RES);
            ix = min(RES - 1, max(0, ix));
            iy = min(RES - 1, max(0, iy));
            iz = min(RES - 1, max(0, iz));
            const int gi = b * GCELLS + (ix << 10) + (iy << 5) + iz;
            const float v  = vox[gi];
            const float dx = qx - aux[gi*3+0] + EPS_PD;
            const float dy = qy - aux[gi*3+1] + EPS_PD;
            const float dz = qz - aux[gi*3+2] + EPS_PD;
            acc += sqrtf(dx*dx + dy*dy + dz*dz) * (1.0f - v);
        }
    }

    #pragma unroll
    for (int off = 32; off > 0; off >>= 1)
        acc += __shfl_down(acc, off);

    __shared__ float ws[4];
    if ((threadIdx.x & 63) == 0) ws[threadIdx.x >> 6] = acc;
    __syncthreads();
    if (threadIdx.x == 0)
        part[blockIdx.x] = ws[0] + ws[1] + ws[2] + ws[3];
}

// ---------------------------------------------------------------------------
extern "C" void kernel_launch(void* const* d_in, const int* in_sizes, int n_in,
                              void* d_out, int out_size, void* d_ws, size_t ws_size,
                              hipStream_t stream)
{
    const float* pc     = (const float*)d_in[0];
    const float* aux    = (const float*)d_in[1];
    const float* vox    = (const float*)d_in[2];
    const float* planes = (const float*)d_in[3];
    float* out = (float*)d_out;

    if (ws_size >= PACKED_BYTES + NB * sizeof(float)) {
        u16*   packed = (u16*)d_ws;
        float* part   = (float*)((char*)d_ws + PACKED_BYTES);
        pack_u16_kernel<<<PACK_BLOCKS, 256, 0, stream>>>(aux, vox, packed);
        sym_lds_kernel<<<NB, NT, 0, stream>>>(pc, packed, planes, part);
        finalize_kernel<<<1, 512, 0, stream>>>(part, planes, out);
    } else {
        float* part = (float*)d_ws;
        sym_fallback_kernel<<<PACK_BLOCKS, 256, 0, stream>>>(pc, aux, vox, planes, part);
        finalize_fb_kernel<<<1, 256, 0, stream>>>(part, PACK_BLOCKS, planes, out);
    }
}

// Round 14
// 23.911 us; speedup vs baseline: 8.8934x; 1.0122x over previous
//
#include <hip/hip_runtime.h>
#include <math.h>

#define RES     32
#define GCELLS  (RES * RES * RES)       // 32768
#define NPTS    32768
#define BATCH   64
#define NPLANES 3
#define EPS_PD  1e-6f
#define WREG_F  25.0f

#define NB      512                     // sym blocks: 2 per CU (32 waves = max)
#define NT      1024
#define NWAVES  (NT / 64)

#define PACK_BLOCKS 2048
#define PACKED_BYTES ((size_t)BATCH * GCELLS * 2)    // 4 MiB (u16/cell)

typedef float          f4 __attribute__((ext_vector_type(4)));
typedef unsigned int   u32;
typedef unsigned short u16;
typedef u32            u4 __attribute__((ext_vector_type(4)));
typedef u32            u2 __attribute__((ext_vector_type(2)));

// ---------------------------------------------------------------------------
// helpers
// ---------------------------------------------------------------------------
__device__ __forceinline__ u32 quant_cell4(float x, float y, float z, float v) {
    // 4-bit each: u = round_half_up((c+0.5)*15) = floor(c*15 + 8); v: round(v*15)
    const u32 ux = (u32)fmaf(x, 15.0f, 8.0f);
    const u32 uy = (u32)fmaf(y, 15.0f, 8.0f);
    const u32 uz = (u32)fmaf(z, 15.0f, 8.0f);
    const u32 uv = (u32)fmaf(v, 15.0f, 0.5f);
    return ux | (uy << 4) | (uz << 8) | (uv << 12);
}

__device__ __forceinline__ float reg_term(const float* __restrict__ planes, int b) {
    float nv[3][3];
    #pragma unroll
    for (int p = 0; p < NPLANES; ++p) {
        const float nxv = planes[((p * BATCH + b) << 2) + 0];
        const float nyv = planes[((p * BATCH + b) << 2) + 1];
        const float nzv = planes[((p * BATCH + b) << 2) + 2];
        float nrm = fmaxf(sqrtf(nxv*nxv + nyv*nyv + nzv*nzv), 1e-12f);
        nv[p][0] = nxv / nrm; nv[p][1] = nyv / nrm; nv[p][2] = nzv / nrm;
    }
    float r = 0.0f;
    #pragma unroll
    for (int i = 0; i < 3; ++i)
        #pragma unroll
        for (int j = 0; j < 3; ++j) {
            const float m = nv[i][j] * nv[j][i] - (i == j ? 1.0f : 0.0f);
            r += m * m;
        }
    return r;
}

// ---------------------------------------------------------------------------
// Kernel 1: quantize (aux.xyz, vox) -> u16 table (4 bits/field), XCD-swizzled.
// Block 0 additionally initializes out[0] with the regularizer term; the
// pack->sym kernel boundary orders this before any sym atomicAdd. Each
// replay rewrites out[0], so no cross-replay accumulation.
// ---------------------------------------------------------------------------
__device__ __forceinline__ int swizzle_chunk(int bid) {
    return (bid & 7) * (PACK_BLOCKS / 8) + (bid >> 3);
}

__global__ __launch_bounds__(256) void pack_u16_kernel(
    const float* __restrict__ aux,
    const float* __restrict__ vox,
    const float* __restrict__ planes,
    u16* __restrict__ packed,
    float* __restrict__ out)
{
    if (blockIdx.x == 0) {
        __shared__ float rsum[1];
        if (threadIdx.x == 0) rsum[0] = 0.0f;
        __syncthreads();
        if (threadIdx.x < 64) {
            float r = reg_term(planes, threadIdx.x) * (WREG_F / (float)BATCH);
            #pragma unroll
            for (int off = 32; off > 0; off >>= 1)
                r += __shfl_down(r, off);
            if (threadIdx.x == 0) rsum[0] = r;
        }
        __syncthreads();
        if (threadIdx.x == 0) out[0] = rsum[0];
    }

    const int chunk = swizzle_chunk(blockIdx.x);
    const int i = chunk * 256 + threadIdx.x;        // group of 4 cells

    const f4* a4 = (const f4*)aux + (size_t)i * 3;
    const f4 a = a4[0];
    const f4 b = a4[1];
    const f4 c = a4[2];
    const f4 v = ((const f4*)vox)[i];

    const u32 c0 = quant_cell4(a.x, a.y, a.z, v.x);
    const u32 c1 = quant_cell4(a.w, b.x, b.y, v.y);
    const u32 c2 = quant_cell4(b.z, b.w, c.x, v.z);
    const u32 c3 = quant_cell4(c.y, c.z, c.w, v.w);

    u2 o;
    o[0] = c0 | (c1 << 16);
    o[1] = c2 | (c3 << 16);
    *((u2*)packed + i) = o;            // 8-B store: table stays in this L2
}

// ---------------------------------------------------------------------------
// Kernel 2: 512 blocks (2/CU = 32 waves/CU, HW max), 64 KB LDS table staged
// conflict-free, 4 pts/thread, compiler-interleaved gather. One fp32
// atomicAdd per block into out[0] (fire-and-forget, overlaps other blocks).
// ---------------------------------------------------------------------------
__global__ __launch_bounds__(NT, 8) void sym_lds_kernel(
    const float* __restrict__ pc,      // (B, N, 3)
    const u16* __restrict__ packed,    // (B*G) u16
    const float* __restrict__ planes,  // (3, B, 4)
    float* __restrict__ out)
{
    __shared__ u16   tab[GCELLS];      // 64 KiB
    __shared__ float wsum[NWAVES];

    const int t    = threadIdx.x;
    const int blk  = blockIdx.x;
    const int xcd  = blk & 7;
    const int slot = blk >> 3;                 // 0..63 on this XCD
    const int b    = xcd * 8 + (slot >> 3);    // batch (8 blocks/batch, same XCD)
    const int c    = slot & 7;                 // eighth of the batch's points

    // ---- pc loads first: latency hides under table staging ----
    const f4* pc4 = (const f4*)pc
                  + (((size_t)(b * NPTS + c * 4096) * 3) >> 2)
                  + (size_t)t * 3;
    f4 A[3];
    #pragma unroll
    for (int i = 0; i < 3; ++i) A[i] = pc4[i];

    // ---- stage 64 KB table: 16 x (dword load + b32 LDS write), 4 B/lane
    //      stride -> consecutive banks -> conflict-free ----
    const u32* gt32  = (const u32*)packed + (size_t)b * (GCELLS / 2);
    u32*       tab32 = (u32*)tab;
    #pragma unroll
    for (int i = 0; i < 16; ++i) {
        const int k = i * NT + t;
        tab32[k] = gt32[k];
    }

    // ---- block-uniform plane constants (sc folded into normals) ----
    float nx[3], ny[3], nz[3], dd[3], mx[3], my[3], mz[3];
    #pragma unroll
    for (int pl = 0; pl < NPLANES; ++pl) {
        const float* P = planes + ((pl * BATCH + b) << 2);
        nx[pl] = P[0]; ny[pl] = P[1]; nz[pl] = P[2]; dd[pl] = P[3];
        const float sc = 2.0f / (nx[pl]*nx[pl] + ny[pl]*ny[pl] + nz[pl]*nz[pl]);
        mx[pl] = sc * nx[pl]; my[pl] = sc * ny[pl]; mz[pl] = sc * nz[pl];
    }

    __syncthreads();

    const float* f = (const float*)A;
    const float SHIFT = 0.5f + EPS_PD;         // fold +0.5 and +eps into q
    const float IOFF  = -32.0f * EPS_PD;       // undo eps in the index path
    const float INV15 = 1.0f / 15.0f;

    // ---- gather loop: 4 points x 3 planes, compiler-interleaved ----
    float acc = 0.0f;
    #pragma unroll
    for (int p = 0; p < 4; ++p) {
        const float px = f[3*p], py = f[3*p+1], pz = f[3*p+2];
        const float pxs = px + SHIFT, pys = py + SHIFT, pzs = pz + SHIFT;
        #pragma unroll
        for (int pl = 0; pl < NPLANES; ++pl) {
            // tt' = dot(p,n) + d  (3 fma); q = p - tt' * (sc*n)
            const float tt  = fmaf(pz, nz[pl], fmaf(py, ny[pl],
                              fmaf(px, nx[pl], dd[pl])));
            const float qxs = fmaf(-tt, mx[pl], pxs);   // qx + 0.5 + eps
            const float qys = fmaf(-tt, my[pl], pys);
            const float qzs = fmaf(-tt, mz[pl], pzs);
            int ix = (int)fmaf(qxs, 32.0f, IOFF);
            int iy = (int)fmaf(qys, 32.0f, IOFF);
            int iz = (int)fmaf(qzs, 32.0f, IOFF);
            ix = min(max(ix, 0), RES - 1);
            iy = min(max(iy, 0), RES - 1);
            iz = min(max(iz, 0), RES - 1);
            const u32 g    = ((u32)ix << 10) + ((u32)iy << 5) + (u32)iz;
            const u32 cell = (u32)tab[g];
            const float dx = fmaf((float)(cell & 15u),        -INV15, qxs);
            const float dy = fmaf((float)((cell >> 4) & 15u), -INV15, qys);
            const float dz = fmaf((float)((cell >> 8) & 15u), -INV15, qzs);
            const float w  = fmaf((float)(cell >> 12),        -INV15, 1.0f);
            acc = fmaf(__builtin_amdgcn_sqrtf(dx*dx + dy*dy + dz*dz), w, acc);
        }
    }

    // ---- block reduce, then one atomicAdd into out[0] ----
    #pragma unroll
    for (int off = 32; off > 0; off >>= 1)
        acc += __shfl_down(acc, off);
    if ((t & 63) == 0) wsum[t >> 6] = acc;
    __syncthreads();
    if (t == 0) {
        float s = 0.0f;
        #pragma unroll
        for (int w = 0; w < NWAVES; ++w) s += wsum[w];
        atomicAdd(out, s * (1.0f / (float)BATCH));
    }
}

// ---------------------------------------------------------------------------
// Fallback (ws too small): direct fp32 gathers + separate finalize.
// ---------------------------------------------------------------------------
__global__ __launch_bounds__(256) void finalize_fb_kernel(
    const float* __restrict__ part, int n_part,
    const float* __restrict__ planes,
    float* __restrict__ out)
{
    __shared__ float sdata[256];

    float s = 0.0f;
    for (int i = threadIdx.x; i < n_part; i += 256)
        s += part[i];

    float r = 0.0f;
    if (threadIdx.x < BATCH)
        r = reg_term(planes, threadIdx.x);

    float val = s * (1.0f / (float)BATCH) + r * (WREG_F / (float)BATCH);

    sdata[threadIdx.x] = val;
    __syncthreads();
    #pragma unroll
    for (int off = 128; off > 0; off >>= 1) {
        if (threadIdx.x < off) sdata[threadIdx.x] += sdata[threadIdx.x + off];
        __syncthreads();
    }
    if (threadIdx.x == 0) out[0] = sdata[0];
}

__global__ __launch_bounds__(256) void sym_fallback_kernel(
    const float* __restrict__ pc,
    const float* __restrict__ aux,
    const float* __restrict__ vox,
    const float* __restrict__ planes,
    float* __restrict__ part)
{
    const int chunk = swizzle_chunk(blockIdx.x);
    const int b  = chunk >> 5;
    const int cb = chunk & 31;

    float nx[3], ny[3], nz[3], dd[3], sc[3];
    #pragma unroll
    for (int pl = 0; pl < NPLANES; ++pl) {
        const float* P = planes + ((pl * BATCH + b) << 2);
        nx[pl] = P[0]; ny[pl] = P[1]; nz[pl] = P[2]; dd[pl] = P[3];
        sc[pl] = 2.0f / (nx[pl]*nx[pl] + ny[pl]*ny[pl] + nz[pl]*nz[pl]);
    }

    const int p0 = b * NPTS + cb * 1024 + threadIdx.x * 4;
    const f4* pc4 = (const f4*)pc + (size_t)(p0 >> 2) * 3;
    const f4 A  = pc4[0];
    const f4 Bv = pc4[1];
    const f4 C  = pc4[2];

    const float px[4] = {A.x, A.w, Bv.z, C.y};
    const float py[4] = {A.y, Bv.x, Bv.w, C.z};
    const float pz[4] = {A.z, Bv.y, C.x, C.w};

    float acc = 0.0f;
    #pragma unroll
    for (int pt = 0; pt < 4; ++pt) {
        #pragma unroll
        for (int pl = 0; pl < NPLANES; ++pl) {
            const float tt = (px[pt]*nx[pl] + py[pt]*ny[pl] + pz[pt]*nz[pl]
                              + dd[pl]) * sc[pl];
            const float qx = px[pt] - tt * nx[pl];
            const float qy = py[pt] - tt * ny[pl];
            const float qz = pz[pt] - tt * nz[pl];
            int ix = (int)((qx + 0.5f) * (float)RES);
            int iy = (int)((qy + 0.5f) * (float)RES);
            int iz = (int)((qz + 0.5f) * (float)RES);
            ix = min(RES - 1, max(0, ix));
            iy = min(RES - 1, max(0, iy));
            iz = min(RES - 1, max(0, iz));
            const int gi = b * GCELLS + (ix << 10) + (iy << 5) + iz;
            const float v  = vox[gi];
            const float dx = qx - aux[gi*3+0] + EPS_PD;
            const float dy = qy - aux[gi*3+1] + EPS_PD;
            const float dz = qz - aux[gi*3+2] + EPS_PD;
            acc += sqrtf(dx*dx + dy*dy + dz*dz) * (1.0f - v);
        }
    }

    #pragma unroll
    for (int off = 32; off > 0; off >>= 1)
        acc += __shfl_down(acc, off);

    __shared__ float ws[4];
    if ((threadIdx.x & 63) == 0) ws[threadIdx.x >> 6] = acc;
    __syncthreads();
    if (threadIdx.x == 0)
        part[blockIdx.x] = ws[0] + ws[1] + ws[2] + ws[3];
}

// ---------------------------------------------------------------------------
extern "C" void kernel_launch(void* const* d_in, const int* in_sizes, int n_in,
                              void* d_out, int out_size, void* d_ws, size_t ws_size,
                              hipStream_t stream)
{
    const float* pc     = (const float*)d_in[0];
    const float* aux    = (const float*)d_in[1];
    const float* vox    = (const float*)d_in[2];
    const float* planes = (const float*)d_in[3];
    float* out = (float*)d_out;

    if (ws_size >= PACKED_BYTES) {
        u16* packed = (u16*)d_ws;
        pack_u16_kernel<<<PACK_BLOCKS, 256, 0, stream>>>(aux, vox, planes, packed, out);
        sym_lds_kernel<<<NB, NT, 0, stream>>>(pc, packed, planes, out);
    } else {
        float* part = (float*)d_ws;
        sym_fallback_kernel<<<PACK_BLOCKS, 256, 0, stream>>>(pc, aux, vox, planes, part);
        finalize_fb_kernel<<<1, 256, 0, stream>>>(part, PACK_BLOCKS, planes, out);
    }
}